// Round 8
// baseline (938.160 us; speedup 1.0000x reference)
//
#include <hip/hip_runtime.h>
#include <hip/hip_fp16.h>

// CLDice loss, round 12: fused-2 packed (round-11, 919us verified) + SINGLE
// barrier per z-step via double-buffered LDS planes.
// Round-7 post-mortem: fused pair = 167us wall = exactly 2x unfused; HBM 2.2TB/s
// (not the pacer); VALU busy/iter ~constant at ~50us with util 56% => regime is
// VALU-issue + barrier-drain. In fused2p ALL LDS reads are same-step as writes:
// B1 (write->read) is essential, B2 only guards write-after-read. Double-buffer
// sA/sE1/sE2 by step parity => WAR hazard gone, B2 deleted, 48->24 barriers/pair.
// Race-free: wave reaches B1(s+1) only after its C(s) ds_reads drained
// (lgkmcnt(0) at barrier); W(s+2) overwrite of buf[s&1] is after B1(s+1).
// #pragma unroll 2 makes buffer parity static and renames ~32 ring-shift movs.
// Numerics identical to round-11 (absmax 0.0 verified).
// Tail (k=10) = round-4 verified packed MODE-2 kernel, unchanged.

#define ZD 192
#define YD 192
#define XD 192
constexpr int PLANE = YD * XD;
constexpr int VOL   = ZD * PLANE;
constexpr int NVOL4 = 4 * VOL;

constexpr int XT = 64, YT = 16, ZCH = 16;

// ---- fused-2 geometry ----
constexpr int AWQ = 18, SA_Q = 19, AH = 22;   // a: rows y0-3..y0+18, quads x0-4+4c
constexpr int NAQ = AH * AWQ;                 // 396
constexpr int EWQ = 17, SE_Q = 17;            // e1/e2: 17 real quads, odd stride
constexpr int E1H = 20;                       // e1: rows y0-2..y0+17, quads x0-2+4c
constexpr int NE1Q = E1H * EWQ;               // 340
constexpr int E2H = 18;                       // e2: rows y0-1..y0+16, quads x0-1+4c
constexpr int NE2Q = E2H * EWQ;               // 306
constexpr int F2STEPS = ZCH + 8;              // 24; emission at s>=8, zo=z-5
constexpr int SAW2 = SA_Q * 2;                // hv2 row strides
constexpr int SEW2 = SE_Q * 2;

// ---- tail (single-iteration, round-4 verified) geometry ----
constexpr int IWQ = 18, SIW = 19;
constexpr int IH  = 20;
constexpr int NIMGQ = IH * IWQ;               // 360
constexpr int BWQ = 17, BH = 18;
constexpr int NBQ  = BH * BWQ;                // 306
constexpr int TSTEPS = ZCH + 4;               // 20
#define PINF __builtin_inff()

typedef _Float16 hv2 __attribute__((ext_vector_type(2)));
struct __align__(8) H4 { hv2 lo, hi; };       // 4 halfs = 8 B = one "quad"

__device__ __forceinline__ unsigned h2u(hv2 h) { return __builtin_bit_cast(unsigned, h); }
__device__ __forceinline__ hv2 u2h(unsigned u) { return __builtin_bit_cast(hv2, u); }

__device__ __forceinline__ hv2 h2min(hv2 a, hv2 b) {
#if __has_builtin(__builtin_elementwise_min)
    return __builtin_elementwise_min(a, b);
#else
    unsigned r, ua = h2u(a), ub = h2u(b);
    asm("v_pk_min_f16 %0, %1, %2" : "=v"(r) : "v"(ua), "v"(ub));
    return u2h(r);
#endif
}
__device__ __forceinline__ hv2 h2max(hv2 a, hv2 b) {
#if __has_builtin(__builtin_elementwise_max)
    return __builtin_elementwise_max(a, b);
#else
    unsigned r, ua = h2u(a), ub = h2u(b);
    asm("v_pk_max_f16 %0, %1, %2" : "=v"(r) : "v"(ua), "v"(ub));
    return u2h(r);
#endif
}
// {c.y, n.x}: one-element left shift across a packed pair boundary
__device__ __forceinline__ hv2 shf1(hv2 c, hv2 n) {
    return u2h(__builtin_amdgcn_alignbit(h2u(n), h2u(c), 16));
}
__device__ __forceinline__ H4 h4min(H4 a, H4 b) { H4 r; r.lo = h2min(a.lo, b.lo); r.hi = h2min(a.hi, b.hi); return r; }
__device__ __forceinline__ H4 h4max(H4 a, H4 b) { H4 r; r.lo = h2max(a.lo, b.lo); r.hi = h2max(a.hi, b.hi); return r; }
__device__ __forceinline__ H4 pk4(float4 v) {
    H4 r;
    r.lo.x = (_Float16)v.x; r.lo.y = (_Float16)v.y;
    r.hi.x = (_Float16)v.z; r.hi.y = (_Float16)v.w;
    return r;
}
__device__ __forceinline__ H4 ldp4(const __half* p) {
    const uint2 v = *(const uint2*)p;
    H4 r; r.lo = u2h(v.x); r.hi = u2h(v.y); return r;
}
__device__ __forceinline__ void stp4(__half* p, H4 v) {
    uint2 u; u.x = h2u(v.lo); u.y = h2u(v.hi);
    *(uint2*)p = u;
}
__device__ __forceinline__ void sth4(__half* p, float4 v) { stp4(p, pk4(v)); }

// ============================ fused-2 packed kernel (single-barrier) ============================
// MODE 0: first pair (k=0,1): a0 built inline from logits/targets, skel = delta0 then delta1.
// MODE 1: mid pair: read a_k + skel, write a_{k+2} + skel.
template <int MODE>
__global__ __launch_bounds__(256)
void fused2p_kernel(const __half* __restrict__ a_in,
                    __half* __restrict__ a_out,
                    __half* __restrict__ skel,
                    const float* __restrict__ logits,
                    const int* __restrict__ targets)
{
    __shared__ __align__(16) hv2 sA [2][AH  * SA_Q * 2];       // 2 x 836 hv2
    __shared__ __align__(16) hv2 sE1[2][E1H * SE_Q * 2 + 2];   // 2 x 682 hv2 (+2 edge pad)
    __shared__ __align__(16) hv2 sE2[2][E2H * SE_Q * 2];       // 2 x 612 hv2

    const int tx = threadIdx.x, ty = threadIdx.y;   // (16,16)
    const int tid = ty * 16 + tx;
    const int x0 = (blockIdx.x % 3) * XT, y0 = (blockIdx.x / 3) * YT;
    const int z0 = blockIdx.y * ZCH;
    const int zf = blockIdx.z;                      // 0..3
    const int bb = zf & 1, field = zf >> 1;
    const size_t voff = (size_t)zf * VOL;
    const __half* inb  = a_in  + voff;
    __half*       outb = a_out + voff;
    __half*       skb  = skel  + voff;
    const float* lg0 = logits + (size_t)(bb * 2) * VOL;
    const float* lg1 = lg0 + VOL;
    const int*   tgb = targets + (size_t)bb * VOL;

    const hv2 INF2  = u2h(0x7C007C00u);
    const hv2 NINF2 = u2h(0xFC00FC00u);
    const hv2 Z2    = u2h(0u);
    const H4 HINF4  = { INF2, INF2 };
    const H4 HNINF4 = { NINF2, NINF2 };
    const H4 HZ4    = { Z2, Z2 };
    const _Float16 HN1 = (_Float16)(-PINF);

    const int q1off = ((tid & 3) << 6) + (tid >> 2);  // balanced 2nd-chunk id

    // ---- a-plane chunks: qi -> (r=qi/18, c=qi%18); covers (y0-3+r, x0-4+4c)
    int a_ad[2], a_go[2]; bool a_ok[2], a_h[2];
    #pragma unroll
    for (int j = 0; j < 2; ++j) {
        const int qi = (j == 0) ? tid : 256 + q1off;
        const int r = qi / AWQ, c = qi - r * AWQ;
        const int gy = y0 - 3 + r, gxb = x0 - 4 + 4 * c;
        a_h[j]  = (qi < NAQ);
        a_ok[j] = a_h[j] && gy >= 0 && gy < YD && gxb >= 0 && gxb < XD;
        a_go[j] = gy * XD + gxb;
        a_ad[j] = (r * SA_Q + c) * 2;
    }
    // ---- e1 chunks: store into sE1, read from sA; stored +INF outside volume
    int e1st[2], e1rd[2]; bool e1h[2]; H4 e1m[2];
    #pragma unroll
    for (int j = 0; j < 2; ++j) {
        const int qi = (j == 0) ? tid : 256 + q1off;
        const int r = qi / EWQ, c = qi - r * EWQ;
        e1h[j]  = (qi < NE1Q);
        e1st[j] = (r * SE_Q + c) * 2;
        e1rd[j] = (r * SA_Q + c) * 2;
        const int gy = y0 - 2 + r, gxb = x0 - 2 + 4 * c;
        const bool yv = (gy >= 0 && gy < YD);
        float4 m;    // stored e1 = max(v, m): valid -> -INF (keep), invalid -> +INF
        m.x = (yv && gxb     >= 0 && gxb     < XD) ? -PINF : PINF;
        m.y = (yv && gxb + 1 >= 0 && gxb + 1 < XD) ? -PINF : PINF;
        m.z = (yv && gxb + 2 >= 0 && gxb + 2 < XD) ? -PINF : PINF;
        m.w = (yv && gxb + 3 >= 0 && gxb + 3 < XD) ? -PINF : PINF;
        e1m[j] = pk4(m);
    }
    // ---- e2 chunks: store into sE2, read from sE1; stored -INF outside volume
    int e2st[2], e2rd[2]; bool e2h[2]; H4 e2m[2];
    #pragma unroll
    for (int j = 0; j < 2; ++j) {
        const int qi = (j == 0) ? tid : 256 + q1off;
        const int r = qi / EWQ, c = qi - r * EWQ;
        e2h[j]  = (qi < NE2Q);
        e2st[j] = (r * SE_Q + c) * 2;
        e2rd[j] = (r * SE_Q + c) * 2;
        const int gy = y0 - 1 + r, gxb = x0 - 1 + 4 * c;
        const bool yv = (gy >= 0 && gy < YD);
        float4 m;    // stored e2 = min(v, m): valid -> +INF (keep), invalid -> -INF
        m.x = (yv && gxb     >= 0 && gxb     < XD) ? PINF : -PINF;
        m.y = (yv && gxb + 1 >= 0 && gxb + 1 < XD) ? PINF : -PINF;
        m.z = (yv && gxb + 2 >= 0 && gxb + 2 < XD) ? PINF : -PINF;
        m.w = (yv && gxb + 3 >= 0 && gxb + 3 < XD) ? PINF : -PINF;
        e2m[j] = pk4(m);
    }

    // ---- output-quad boundary bools (dilate-on-e1 consumer masks)
    const int gy0 = y0 + ty, gx0 = x0 + 4 * tx;
    const bool rok0 = (gy0 > 0), rok2 = (gy0 < YD - 1);
    const bool lok  = (gx0 > 0), rokx = (gx0 + 4 < XD);

    auto loadq = [&](int zi, int j) -> H4 {
        if (zi < 0 || zi >= ZD || zi > z0 + ZCH + 2 || !a_ok[j]) return HINF4;
        const size_t p = (size_t)zi * PLANE + a_go[j];
        if constexpr (MODE == 0) {
            if (field) {
                const int4 t = *(const int4*)(tgb + p);
                return pk4(make_float4(t.x == 1 ? 1.f : 0.f, t.y == 1 ? 1.f : 0.f,
                                       t.z == 1 ? 1.f : 0.f, t.w == 1 ? 1.f : 0.f));
            } else {
                const float4 a = *(const float4*)(lg0 + p);
                const float4 b = *(const float4*)(lg1 + p);
                return pk4(make_float4(1.f / (1.f + __expf(a.x - b.x)),
                                       1.f / (1.f + __expf(a.y - b.y)),
                                       1.f / (1.f + __expf(a.z - b.z)),
                                       1.f / (1.f + __expf(a.w - b.w))));
            }
        } else {
            return ldp4(inb + p);
        }
    };

    // xy-erode a->e1 at e1 slot j from plane pA
    auto s1p = [&](const hv2* pA, int j) -> H4 {
        const hv2* p = pA + e1rd[j];
        const H4 A0 = *(const H4*)p;
        const H4 B0 = *(const H4*)(p + 2);
        const H4 A1 = *(const H4*)(p + SAW2);
        const H4 B1 = *(const H4*)(p + SAW2 + 2);
        const H4 A2 = *(const H4*)(p + 2 * SAW2);
        const H4 B2 = *(const H4*)(p + 2 * SAW2 + 2);
        const hv2 Al = h2min(A0.lo, h2min(A1.lo, A2.lo));   // {a0,a1}
        const hv2 Ah = h2min(A0.hi, h2min(A1.hi, A2.hi));   // {a2,a3}
        const hv2 Bl = h2min(B0.lo, h2min(B1.lo, B2.lo));   // {b0,b1}
        const hv2 Bh = h2min(B0.hi, h2min(B1.hi, B2.hi));   // {b2,b3}
        const hv2 M1 = shf1(Al, Ah);   // {a1,a2}
        const hv2 M2 = shf1(Ah, Bl);   // {a3,b0}
        const hv2 M3 = shf1(Bl, Bh);   // {b1,b2}
        H4 r;
        r.lo = h2min(M1, h2min(Ah, M2));
        r.hi = h2min(M2, h2min(Bl, M3));
        return r;
    };
    // xy-erode e1->e2 at e2 slot j from plane pE1
    auto s2p = [&](const hv2* pE1, int j) -> H4 {
        const hv2* p = pE1 + e2rd[j];
        const H4 E0 = *(const H4*)p;
        const hv2 F0 = p[2];
        const H4 E1 = *(const H4*)(p + SEW2);
        const hv2 F1 = p[SEW2 + 2];
        const H4 E2 = *(const H4*)(p + 2 * SEW2);
        const hv2 F2 = p[2 * SEW2 + 2];
        const hv2 El = h2min(E0.lo, h2min(E1.lo, E2.lo));
        const hv2 Eh = h2min(E0.hi, h2min(E1.hi, E2.hi));
        const hv2 Fl = h2min(F0, h2min(F1, F2));
        const hv2 M1 = shf1(El, Eh);   // {e1,e2}
        const hv2 M2 = shf1(Eh, Fl);   // {e3,f0}
        H4 r;
        r.lo = h2min(El, h2min(M1, Eh));
        r.hi = h2min(Eh, h2min(M2, Fl));
        return r;
    };

    // rings
    H4 s1p2a = HINF4, s1p1a = HINF4, s1p2b = HINF4, s1p1b = HINF4;
    H4 s2p2a = HINF4, s2p1a = HINF4, s2p2b = HINF4, s2p1b = HINF4;
    H4 xm1p2 = HNINF4, xm1p1 = HNINF4;
    H4 xm2p2 = HNINF4, xm2p1 = HNINF4;
    H4 e1w0 = HINF4, e1w1 = HINF4, e2w0 = HINF4, e2w1 = HINF4;
    H4 icp1 = HZ4, icp2 = HZ4, icp3 = HZ4;
    H4 ec1 = HZ4, ec2 = HZ4, ec3 = HZ4;
    H4 e2cp = HZ4;
    H4 dl1r1 = HZ4, dl1r2 = HZ4;

    const size_t eb = (size_t)gy0 * XD + gx0;

    H4 ca0 = loadq(z0 - 3, 0);
    H4 ca1 = loadq(z0 - 3, 1);

    #pragma unroll 2
    for (int s = 0; s < F2STEPS; ++s) {
        const int z = z0 - 3 + s;      // a-plane z stored this step
        hv2* pA  = sA [s & 1];
        hv2* pE1 = sE1[s & 1];
        hv2* pE2 = sE2[s & 1];
        // ---------- W phase (writes go to this step's parity buffer) ----------
        *(H4*)&pA[a_ad[0]] = ca0;
        if (a_h[1]) *(H4*)&pA[a_ad[1]] = ca1;
        if (s >= 1) {                  // e1(z-2), computed last step
            *(H4*)&pE1[e1st[0]] = h4max(e1w0, e1m[0]);
            if (e1h[1]) *(H4*)&pE1[e1st[1]] = h4max(e1w1, e1m[1]);
        }
        if (s >= 2) {                  // e2(z-4), computed last step
            *(H4*)&pE2[e2st[0]] = h4min(e2w0, e2m[0]);
            if (e2h[1]) *(H4*)&pE2[e2st[1]] = h4min(e2w1, e2m[1]);
        }
        __syncthreads();               // B1: this parity's planes ready
        // (no second barrier: next step writes the OTHER parity; overwrite of
        //  this parity happens after the next B1, by which time all waves have
        //  drained their reads -- WAR hazard eliminated by double buffering)

        // ---------- C phase (all reads from this step's parity buffer) ----------
        if (s + 1 < F2STEPS) { ca0 = loadq(z + 1, 0); ca1 = loadq(z + 1, 1); }

        // stage 1: e1 candidate for z-1 (held, stored next step)
        {
            const H4 cur = s1p(pA, 0);
            e1w0 = h4min(s1p2a, h4min(s1p1a, cur));
            s1p2a = s1p1a; s1p1a = cur;
        }
        if (e1h[1]) {
            const H4 cur = s1p(pA, 1);
            e1w1 = h4min(s1p2b, h4min(s1p1b, cur));
            s1p2b = s1p1b; s1p1b = cur;
        }

        const int  ze1 = z - 2;
        const bool ve1 = (s >= 1) && (ze1 >= 0) && (ze1 < ZD);

        // stage 2a: e2 candidate for z-3
        {
            const H4 cur = ve1 ? s2p(pE1, 0) : HINF4;
            e2w0 = h4min(s2p2a, h4min(s2p1a, cur));
            s2p2a = s2p1a; s2p1a = cur;
        }
        if (e2h[1]) {
            const H4 cur = ve1 ? s2p(pE1, 1) : HINF4;
            e2w1 = h4min(s2p2b, h4min(s2p1b, cur));
            s2p2b = s2p1b; s2p1b = cur;
        }

        // stage 2b: xy-dilate of e1 at output quad (+ e1 center capture)
        H4 xm1c = HNINF4, e1cc = HZ4;
        if (ve1) {
            const hv2* p = pE1 + ((ty + 1) * SE_Q + tx) * 2;
            H4 A0 = *(const H4*)p;
            H4 Bq0 = *(const H4*)(p + 2);
            const H4 A1 = *(const H4*)(p + SEW2);
            const H4 Bq1 = *(const H4*)(p + SEW2 + 2);
            H4 A2 = *(const H4*)(p + 2 * SEW2);
            H4 Bq2 = *(const H4*)(p + 2 * SEW2 + 2);
            e1cc.lo = A1.hi;            // {a2,a3} = e1 at gx0, gx0+1
            e1cc.hi = Bq1.lo;           // {b0,b1} = e1 at gx0+2, gx0+3
            if (!rok0) { A0 = HNINF4; Bq0 = HNINF4; }
            if (!rok2) { A2 = HNINF4; Bq2 = HNINF4; }
            const hv2 Al = h2max(A0.lo, h2max(A1.lo, A2.lo));
            const hv2 Ah = h2max(A0.hi, h2max(A1.hi, A2.hi));
            const hv2 Bl = h2max(Bq0.lo, h2max(Bq1.lo, Bq2.lo));
            const hv2 Bh = h2max(Bq0.hi, h2max(Bq1.hi, Bq2.hi));
            hv2 M1 = shf1(Al, Ah);      // {a1,a2}; a1 = gx0-1
            const hv2 M2 = shf1(Ah, Bl);
            hv2 M3 = shf1(Bl, Bh);      // {b1,b2}; b2 = gx0+4
            if (!lok)  M1.x = HN1;
            if (!rokx) M3.y = HN1;
            xm1c.lo = h2max(M1, h2max(Ah, M2));
            xm1c.hi = h2max(M2, h2max(Bl, M3));
        }
        const H4 d1v = h4max(xm1p2, h4max(xm1p1, xm1c));   // d1(z-3)
        xm1p2 = xm1p1; xm1p1 = xm1c;

        // stage 3: xy-dilate of e2 at output quad (+ e2 center capture)
        const int  ze2 = z - 4;
        const bool ve2 = (s >= 2) && (ze2 >= 0) && (ze2 < ZD);
        H4 xm2c = HNINF4, e2cc = HZ4;
        if (ve2) {
            const hv2* p = pE2 + (ty * SE_Q + tx) * 2;
            const H4 U0 = *(const H4*)p;
            const hv2 V0 = p[2];
            const H4 U1 = *(const H4*)(p + SEW2);
            const hv2 V1 = p[SEW2 + 2];
            const H4 U2 = *(const H4*)(p + 2 * SEW2);
            const hv2 V2 = p[2 * SEW2 + 2];
            e2cc.lo = shf1(U1.lo, U1.hi);   // {u1,u2} = e2 at gx0, gx0+1
            e2cc.hi = shf1(U1.hi, V1);      // {u3,v0} = e2 at gx0+2, gx0+3
            const hv2 Ul = h2max(U0.lo, h2max(U1.lo, U2.lo));
            const hv2 Uh = h2max(U0.hi, h2max(U1.hi, U2.hi));
            const hv2 Vl = h2max(V0, h2max(V1, V2));
            const hv2 M1 = shf1(Ul, Uh);    // {u1,u2}
            const hv2 M2 = shf1(Uh, Vl);    // {u3,v0}
            xm2c.lo = h2max(Ul, h2max(M1, Uh));
            xm2c.hi = h2max(Uh, h2max(M2, Vl));
        }
        const H4 d2v = h4max(xm2p2, h4max(xm2p1, xm2c));   // d2(z-5)
        xm2p2 = xm2p1; xm2p1 = xm2c;

        const H4 icq = *(const H4*)&pA[((ty + 3) * SA_Q + tx + 1) * 2];  // a(z) center

        // delta_k(z-3) = relu(a_k(z-3) - d1(z-3)); delta_{k+1}(z-5) = relu(e1(z-5) - d2(z-5))
        float4 dl1n, dl2;
        dl1n.x = fmaxf((float)icp3.lo.x - (float)d1v.lo.x, 0.f);
        dl1n.y = fmaxf((float)icp3.lo.y - (float)d1v.lo.y, 0.f);
        dl1n.z = fmaxf((float)icp3.hi.x - (float)d1v.hi.x, 0.f);
        dl1n.w = fmaxf((float)icp3.hi.y - (float)d1v.hi.y, 0.f);
        dl2.x = fmaxf((float)ec3.lo.x - (float)d2v.lo.x, 0.f);
        dl2.y = fmaxf((float)ec3.lo.y - (float)d2v.lo.y, 0.f);
        dl2.z = fmaxf((float)ec3.hi.x - (float)d2v.hi.x, 0.f);
        dl2.w = fmaxf((float)ec3.hi.y - (float)d2v.hi.y, 0.f);
        const H4 dA = dl1r2;   // delta_k(z-5), fp16-packed ring
        const H4 av = e2cp;    // a_{k+2}(z-5)

        // ---------- emission (registers + global only) ----------
        if (s >= 8) {
            const int zo = z - 5;  // in [z0, z0+15]
            const size_t idx = (size_t)zo * PLANE + eb;
            float4 sk;
            const float dAx = (float)dA.lo.x, dAy = (float)dA.lo.y;
            const float dAz = (float)dA.hi.x, dAw = (float)dA.hi.y;
            if constexpr (MODE == 0) {
                sk = make_float4(dAx, dAy, dAz, dAw);      // skel = delta0
            } else {
                const H4 s0 = ldp4(skb + idx);
                const float s0x = (float)s0.lo.x, s0y = (float)s0.lo.y;
                const float s0z = (float)s0.hi.x, s0w = (float)s0.hi.y;
                sk.x = s0x + dAx * (1.f - s0x);
                sk.y = s0y + dAy * (1.f - s0y);
                sk.z = s0z + dAz * (1.f - s0z);
                sk.w = s0w + dAw * (1.f - s0w);
            }
            float4 sv;
            sv.x = sk.x + dl2.x * (1.f - sk.x);
            sv.y = sk.y + dl2.y * (1.f - sk.y);
            sv.z = sk.z + dl2.z * (1.f - sk.z);
            sv.w = sk.w + dl2.w * (1.f - sk.w);
            sth4(skb + idx, sv);
            stp4(outb + idx, av);
        }

        // ---------- ring shifts ----------
        dl1r2 = dl1r1; dl1r1 = pk4(dl1n);
        icp3 = icp2; icp2 = icp1; icp1 = icq;
        ec3 = ec2; ec2 = ec1; ec1 = e1cc;
        e2cp = e2cc;
    }
}

// ============================ tail kernel (round-4 verified; MODE 2 only) ============================
template <int MODE>   // 2 = last (k=10; in-reg skel update + weighted reduce)
__global__ __launch_bounds__(256)
void fused_kernel(const __half* __restrict__ a_in,
                  __half* __restrict__ a_out,
                  __half* __restrict__ skel,
                  const float* __restrict__ logits,
                  const int* __restrict__ targets,
                  float* __restrict__ sums)
{
    __shared__ __align__(16) hv2 simg[2][IH * SIW * 2];
    __shared__ __align__(16) hv2 sbp[NBQ * 2 + 4];
    __shared__ float red[4][2];

    const int tx = threadIdx.x, ty = threadIdx.y;
    const int tid = ty * 16 + tx;
    const int x0 = (blockIdx.x % 3) * XT, y0 = (blockIdx.x / 3) * YT;
    const int z0 = blockIdx.y * ZCH;
    const int zf = blockIdx.z;
    const int bb = zf & 1, field = zf >> 1;
    const size_t voff = (size_t)zf * VOL;
    const __half* inb  = a_in  + voff;
    __half*       skb  = skel  + voff;
    const float* lg0 = logits + (size_t)(bb * 2) * VOL;
    const float* lg1 = lg0 + VOL;
    const int*   tgb = targets + (size_t)bb * VOL;

    const hv2 INF2  = u2h(0x7C007C00u);
    const hv2 NINF2 = u2h(0xFC00FC00u);
    const hv2 Z2    = u2h(0u);
    const H4 HINF4  = { INF2, INF2 };
    const H4 HNINF4 = { NINF2, NINF2 };
    const H4 HZ4    = { Z2, Z2 };

    const int q1off = ((tid & 3) << 6) + (tid >> 2);

    int im_qi[2] = { tid, 256 + q1off };
    int im_addr[2], im_goff[2]; bool im_ok[2], im_has[2];
    #pragma unroll
    for (int j = 0; j < 2; ++j) {
        const int qi = im_qi[j];
        const int r = qi / IWQ, c = qi - r * IWQ;
        const int gy = y0 - 2 + r, gxb = x0 - 4 + 4 * c;
        im_has[j] = (qi < NIMGQ);
        im_ok[j]  = im_has[j] && gy >= 0 && gy < YD && gxb >= 0 && gxb < XD;
        im_goff[j] = gy * XD + gxb;
        im_addr[j] = (r * SIW + c) * 2;
    }
    int bqi[2], brow[2], bcol[2]; bool bhas[2]; H4 bmask[2];
    #pragma unroll
    for (int j = 0; j < 2; ++j) {
        const int qi = (j == 0) ? tid : 256 + q1off;
        bqi[j] = qi;
        bhas[j] = (qi < NBQ);
        const int r = qi / BWQ, c = qi - r * BWQ;
        brow[j] = r; bcol[j] = c;
        const int gy = y0 - 1 + r, gxb = x0 - 1 + 4 * c;
        const bool yv = (gy >= 0 && gy < YD);
        float4 m;
        m.x = (yv && gxb     >= 0 && gxb     < XD) ? PINF : -PINF;
        m.y = (yv && gxb + 1 >= 0 && gxb + 1 < XD) ? PINF : -PINF;
        m.z = (yv && gxb + 2 >= 0 && gxb + 2 < XD) ? PINF : -PINF;
        m.w = (yv && gxb + 3 >= 0 && gxb + 3 < XD) ? PINF : -PINF;
        bmask[j] = pk4(m);
    }

    auto loadq = [&](int zi, int j) -> H4 {
        if (zi < 0 || zi >= ZD || !im_ok[j]) return HINF4;
        const size_t p = (size_t)zi * PLANE + im_goff[j];
        return ldp4(inb + p);
    };

    auto s1_of = [&](const hv2* sp, int j) -> H4 {
        const hv2* p = sp + (brow[j] * SIW + bcol[j]) * 2;
        const hv2 A0 = p[1];
        const hv2 A1 = p[SIW * 2 + 1];
        const hv2 A2 = p[SIW * 4 + 1];
        const H4 B0 = *(const H4*)(p + 2);
        const H4 B1 = *(const H4*)(p + SIW * 2 + 2);
        const H4 B2 = *(const H4*)(p + SIW * 4 + 2);
        const hv2 Ah = h2min(A0, h2min(A1, A2));
        const hv2 Bl = h2min(B0.lo, h2min(B1.lo, B2.lo));
        const hv2 Bh = h2min(B0.hi, h2min(B1.hi, B2.hi));
        const hv2 S1 = shf1(Ah, Bl);
        const hv2 S2 = shf1(Bl, Bh);
        H4 r;
        r.lo = h2min(Ah, h2min(S1, Bl));
        r.hi = h2min(Bl, h2min(S2, Bh));
        return r;
    };

    H4 p2a = HINF4, p1a = HINF4;
    H4 p2b = HINF4, p1b = HINF4;
    H4 s2p1 = HNINF4, s2p2 = HNINF4;
    H4 icp1 = HZ4, icp2 = HZ4;
    float sd = 0.f, ss = 0.f;

    H4 ca0 = loadq(z0 - 2, 0);
    H4 ca1 = loadq(z0 - 2, 1);

    #pragma unroll 2
    for (int s = 0; s < TSTEPS; ++s) {
        const int zi = z0 - 2 + s;
        hv2* sp = simg[s & 1];
        *(H4*)&sp[im_addr[0]] = ca0;
        if (im_has[1]) *(H4*)&sp[im_addr[1]] = ca1;
        if (s + 1 < TSTEPS) { ca0 = loadq(zi + 1, 0); ca1 = loadq(zi + 1, 1); }
        __syncthreads();
        const int zb = zi - 1;
        const bool zbv = (s >= 2) && (zb >= 0) && (zb < ZD);
        {
            const H4 cur = s1_of(sp, 0);
            if (zbv) {
                const H4 b = h4min(h4min(p2a, p1a), cur);
                *(H4*)&sbp[2 * bqi[0]] = h4min(b, bmask[0]);
            }
            p2a = p1a; p1a = cur;
        }
        if (bhas[1]) {
            const H4 cur = s1_of(sp, 1);
            if (zbv) {
                const H4 b = h4min(h4min(p2b, p1b), cur);
                *(H4*)&sbp[2 * bqi[1]] = h4min(b, bmask[1]);
            }
            p2b = p1b; p1b = cur;
        }
        const H4 icq = *(const H4*)&sp[((ty + 2) * SIW + tx + 1) * 2];
        __syncthreads();
        H4 s2n = HNINF4;
        if (zbv) {
            const hv2* p = sbp + (ty * BWQ + tx) * 2;
            const H4 U0 = *(const H4*)p;
            const H4 U1 = *(const H4*)(p + BWQ * 2);
            const H4 U2 = *(const H4*)(p + BWQ * 4);
            const hv2 V0 = p[2];
            const hv2 V1 = p[BWQ * 2 + 2];
            const hv2 V2 = p[BWQ * 4 + 2];
            const hv2 Ul = h2max(U0.lo, h2max(U1.lo, U2.lo));
            const hv2 Uh = h2max(U0.hi, h2max(U1.hi, U2.hi));
            const hv2 Vl = h2max(V0, h2max(V1, V2));
            const hv2 S1 = shf1(Ul, Uh);
            const hv2 S2 = shf1(Uh, Vl);
            s2n.lo = h2max(Ul, h2max(S1, Uh));
            s2n.hi = h2max(Uh, h2max(S2, Vl));
        }
        if (s >= 4) {
            const int zo = zi - 2;
            const H4 d = h4max(s2p2, h4max(s2p1, s2n));
            float4 dl;
            dl.x = fmaxf((float)icp2.lo.x - (float)d.lo.x, 0.f);
            dl.y = fmaxf((float)icp2.lo.y - (float)d.lo.y, 0.f);
            dl.z = fmaxf((float)icp2.hi.x - (float)d.hi.x, 0.f);
            dl.w = fmaxf((float)icp2.hi.y - (float)d.hi.y, 0.f);
            const size_t idx = (size_t)zo * PLANE + (size_t)(y0 + ty) * XD + (x0 + 4 * tx);
            const H4 sk = ldp4(skb + idx);
            const float s0x = (float)sk.lo.x, s0y = (float)sk.lo.y;
            const float s0z = (float)sk.hi.x, s0w = (float)sk.hi.y;
            float4 sv;
            sv.x = s0x + dl.x * (1.f - s0x);
            sv.y = s0y + dl.y * (1.f - s0y);
            sv.z = s0z + dl.z * (1.f - s0z);
            sv.w = s0w + dl.w * (1.f - s0w);
            float4 w;
            if (field) {
                const float4 a = *(const float4*)(lg0 + idx);
                const float4 b = *(const float4*)(lg1 + idx);
                w = make_float4(1.f / (1.f + __expf(a.x - b.x)),
                                1.f / (1.f + __expf(a.y - b.y)),
                                1.f / (1.f + __expf(a.z - b.z)),
                                1.f / (1.f + __expf(a.w - b.w)));
            } else {
                const int4 t = *(const int4*)(tgb + idx);
                w = make_float4(t.x == 1 ? 1.f : 0.f, t.y == 1 ? 1.f : 0.f,
                                t.z == 1 ? 1.f : 0.f, t.w == 1 ? 1.f : 0.f);
            }
            sd += sv.x * w.x + sv.y * w.y + sv.z * w.z + sv.w * w.w;
            ss += sv.x + sv.y + sv.z + sv.w;
        }
        s2p2 = s2p1; s2p1 = s2n;
        icp2 = icp1; icp1 = icq;
    }

    if constexpr (MODE == 2) {
        #pragma unroll
        for (int o = 32; o; o >>= 1) {
            sd += __shfl_down(sd, o, 64);
            ss += __shfl_down(ss, o, 64);
        }
        const int w = tid >> 6;
        if ((tid & 63) == 0) { red[w][0] = sd; red[w][1] = ss; }
        __syncthreads();
        if (tid == 0) {
            float a = 0.f, b = 0.f;
            #pragma unroll
            for (int i = 0; i < 4; ++i) { a += red[i][0]; b += red[i][1]; }
            atomicAdd(&sums[2 * field + 0], a);
            atomicAdd(&sums[2 * field + 1], b);
        }
    }
}

__global__ void final_kernel(const float* __restrict__ sums, float* __restrict__ out)
{
    float tprec = (sums[0] + 1.f) / (sums[1] + 1.f);
    float tsens = (sums[2] + 1.f) / (sums[3] + 1.f);
    float cl = 2.f * tprec * tsens / (tprec + tsens + 1e-7f);
    out[0] = 1.f - cl;
}

extern "C" void kernel_launch(void* const* d_in, const int* in_sizes, int n_in,
                              void* d_out, int out_size, void* d_ws, size_t ws_size,
                              hipStream_t stream)
{
    const float* logits  = (const float*)d_in[0];
    const int*   targets = (const int*)d_in[1];
    float* out  = (float*)d_out;

    float*  sums = (float*)d_ws;
    __half* A    = (__half*)(sums + 16);
    __half* B    = A + NVOL4;
    __half* SK   = B + NVOL4;

    hipMemsetAsync(sums, 0, 16 * sizeof(float), stream);

    dim3 g(3 * (YD / YT), ZD / ZCH, 4);    // (36, 12, 4) = 1728 blocks
    dim3 blk(16, 16, 1);

    // pairs (0,1),(2,3),(4,5),(6,7),(8,9): 5 fused dispatches
    fused2p_kernel<0><<<g, blk, 0, stream>>>(A, A, SK, logits, targets);  // a2 -> A
    fused2p_kernel<1><<<g, blk, 0, stream>>>(A, B, SK, logits, targets);  // a4 -> B
    fused2p_kernel<1><<<g, blk, 0, stream>>>(B, A, SK, logits, targets);  // a6 -> A
    fused2p_kernel<1><<<g, blk, 0, stream>>>(A, B, SK, logits, targets);  // a8 -> B
    fused2p_kernel<1><<<g, blk, 0, stream>>>(B, A, SK, logits, targets);  // a10 -> A
    // k = 10: read a10 (in A), in-reg skel update + weighted reduce
    fused_kernel<2><<<g, blk, 0, stream>>>(A, B, SK, logits, targets, sums);

    final_kernel<<<1, 1, 0, stream>>>(sums, out);
}

// Round 10
// 852.109 us; speedup vs baseline: 1.1010x; 1.1010x over previous
//
#include <hip/hip_runtime.h>
#include <hip/hip_fp16.h>

// CLDice loss, round 13 (resubmit; round-9 bench was an infra failure, no signal).
// Round-7 base (fused-2 packed, 2-barrier, 919us verified)
// + wave-concentrated extra chunks + packed-fp16 emission math.
// Session invariant: per-iteration wall ~83us across 4 schedule variants =>
// pacer is VALU+LDS ISSUE per iteration. This round deletes issued work:
//  1. Extra chunks (a:140, e1:84, e2:50, im:104, b:50 quads beyond 256) mapped to
//     the HIGHEST contiguous tids (qi = tid + N-256, active iff tid >= 512-N)
//     instead of a scattered permutation -> waves 0/1 skip chunk-1 phases via
//     execz; aggregate issue -15-18%; chunk-1 LDS access becomes contiguous.
//  2. Emission (delta + 2 skel updates) in packed v_pk_*_f16 (~8 ops vs ~28 f32
//     + cvts). delta_k was already fp16-rounded (ring); added roundings <=2^-11,
//     unbiased. Tail keeps f32 math (feeds f32 reduction).
// Dataflow identical to round-7 (absmax 0.0 verified).

#define ZD 192
#define YD 192
#define XD 192
constexpr int PLANE = YD * XD;
constexpr int VOL   = ZD * PLANE;
constexpr int NVOL4 = 4 * VOL;

constexpr int XT = 64, YT = 16, ZCH = 16;

// ---- fused-2 geometry ----
constexpr int AWQ = 18, SA_Q = 19, AH = 22;   // a: rows y0-3..y0+18, quads x0-4+4c
constexpr int NAQ = AH * AWQ;                 // 396 -> extras 140, thresh 116
constexpr int EWQ = 17, SE_Q = 17;            // e1/e2: 17 real quads, odd stride
constexpr int E1H = 20;                       // e1: rows y0-2..y0+17, quads x0-2+4c
constexpr int NE1Q = E1H * EWQ;               // 340 -> extras 84, thresh 172
constexpr int E2H = 18;                       // e2: rows y0-1..y0+16, quads x0-1+4c
constexpr int NE2Q = E2H * EWQ;               // 306 -> extras 50, thresh 206
constexpr int F2STEPS = ZCH + 8;              // 24; emission at s>=8, zo=z-5
constexpr int SAW2 = SA_Q * 2;                // hv2 row strides
constexpr int SEW2 = SE_Q * 2;

// ---- tail (single-iteration, round-4 verified) geometry ----
constexpr int IWQ = 18, SIW = 19;
constexpr int IH  = 20;
constexpr int NIMGQ = IH * IWQ;               // 360 -> extras 104, thresh 152
constexpr int BWQ = 17, BH = 18;
constexpr int NBQ  = BH * BWQ;                // 306 -> extras 50, thresh 206
constexpr int TSTEPS = ZCH + 4;               // 20
#define PINF __builtin_inff()

typedef _Float16 hv2 __attribute__((ext_vector_type(2)));
struct __align__(8) H4 { hv2 lo, hi; };       // 4 halfs = 8 B = one "quad"

__device__ __forceinline__ unsigned h2u(hv2 h) { return __builtin_bit_cast(unsigned, h); }
__device__ __forceinline__ hv2 u2h(unsigned u) { return __builtin_bit_cast(hv2, u); }

__device__ __forceinline__ hv2 h2min(hv2 a, hv2 b) {
#if __has_builtin(__builtin_elementwise_min)
    return __builtin_elementwise_min(a, b);
#else
    unsigned r, ua = h2u(a), ub = h2u(b);
    asm("v_pk_min_f16 %0, %1, %2" : "=v"(r) : "v"(ua), "v"(ub));
    return u2h(r);
#endif
}
__device__ __forceinline__ hv2 h2max(hv2 a, hv2 b) {
#if __has_builtin(__builtin_elementwise_max)
    return __builtin_elementwise_max(a, b);
#else
    unsigned r, ua = h2u(a), ub = h2u(b);
    asm("v_pk_max_f16 %0, %1, %2" : "=v"(r) : "v"(ua), "v"(ub));
    return u2h(r);
#endif
}
// {c.y, n.x}: one-element left shift across a packed pair boundary
__device__ __forceinline__ hv2 shf1(hv2 c, hv2 n) {
    return u2h(__builtin_amdgcn_alignbit(h2u(n), h2u(c), 16));
}
__device__ __forceinline__ H4 h4min(H4 a, H4 b) { H4 r; r.lo = h2min(a.lo, b.lo); r.hi = h2min(a.hi, b.hi); return r; }
__device__ __forceinline__ H4 h4max(H4 a, H4 b) { H4 r; r.lo = h2max(a.lo, b.lo); r.hi = h2max(a.hi, b.hi); return r; }
__device__ __forceinline__ H4 pk4(float4 v) {
    H4 r;
    r.lo.x = (_Float16)v.x; r.lo.y = (_Float16)v.y;
    r.hi.x = (_Float16)v.z; r.hi.y = (_Float16)v.w;
    return r;
}
__device__ __forceinline__ H4 ldp4(const __half* p) {
    const uint2 v = *(const uint2*)p;
    H4 r; r.lo = u2h(v.x); r.hi = u2h(v.y); return r;
}
__device__ __forceinline__ void stp4(__half* p, H4 v) {
    uint2 u; u.x = h2u(v.lo); u.y = h2u(v.hi);
    *(uint2*)p = u;
}
__device__ __forceinline__ void sth4(__half* p, float4 v) { stp4(p, pk4(v)); }

// ============================ fused-2 packed kernel ============================
// MODE 0: first pair (k=0,1): a0 built inline from logits/targets, skel = delta0 then delta1.
// MODE 1: mid pair: read a_k + skel, write a_{k+2} + skel.
template <int MODE>
__global__ __launch_bounds__(256)
void fused2p_kernel(const __half* __restrict__ a_in,
                    __half* __restrict__ a_out,
                    __half* __restrict__ skel,
                    const float* __restrict__ logits,
                    const int* __restrict__ targets)
{
    __shared__ __align__(16) hv2 sA [AH  * SA_Q * 2];       // 836 hv2 = 3344 B
    __shared__ __align__(16) hv2 sE1[E1H * SE_Q * 2 + 2];   // 682 hv2 (+2 edge pad)
    __shared__ __align__(16) hv2 sE2[E2H * SE_Q * 2];       // 612 hv2

    const int tx = threadIdx.x, ty = threadIdx.y;   // (16,16)
    const int tid = ty * 16 + tx;
    const int x0 = (blockIdx.x % 3) * XT, y0 = (blockIdx.x / 3) * YT;
    const int z0 = blockIdx.y * ZCH;
    const int zf = blockIdx.z;                      // 0..3
    const int bb = zf & 1, field = zf >> 1;
    const size_t voff = (size_t)zf * VOL;
    const __half* inb  = a_in  + voff;
    __half*       outb = a_out + voff;
    __half*       skb  = skel  + voff;
    const float* lg0 = logits + (size_t)(bb * 2) * VOL;
    const float* lg1 = lg0 + VOL;
    const int*   tgb = targets + (size_t)bb * VOL;

    const hv2 INF2  = u2h(0x7C007C00u);
    const hv2 NINF2 = u2h(0xFC00FC00u);
    const hv2 Z2    = u2h(0u);
    const hv2 ONE2  = u2h(0x3C003C00u);
    const H4 HINF4  = { INF2, INF2 };
    const H4 HNINF4 = { NINF2, NINF2 };
    const H4 HZ4    = { Z2, Z2 };
    const _Float16 HN1 = (_Float16)(-PINF);

    // ---- a-plane chunks: qi -> (r=qi/18, c=qi%18); covers (y0-3+r, x0-4+4c)
    // chunk1 concentrated: qi = tid + (NAQ-256), active iff tid >= 512-NAQ
    int a_ad[2], a_go[2]; bool a_ok[2], a_h[2];
    #pragma unroll
    for (int j = 0; j < 2; ++j) {
        const int qi = (j == 0) ? tid : tid + (NAQ - 256);
        a_h[j] = (j == 0) ? true : (tid >= 512 - NAQ);
        const int r = qi / AWQ, c = qi - r * AWQ;
        const int gy = y0 - 3 + r, gxb = x0 - 4 + 4 * c;
        a_ok[j] = a_h[j] && gy >= 0 && gy < YD && gxb >= 0 && gxb < XD;
        a_go[j] = gy * XD + gxb;
        a_ad[j] = (r * SA_Q + c) * 2;
    }
    // ---- e1 chunks: store into sE1, read from sA; stored +INF outside volume
    int e1st[2], e1rd[2]; bool e1h[2]; H4 e1m[2];
    #pragma unroll
    for (int j = 0; j < 2; ++j) {
        const int qi = (j == 0) ? tid : tid + (NE1Q - 256);
        e1h[j] = (j == 0) ? true : (tid >= 512 - NE1Q);
        const int r = qi / EWQ, c = qi - r * EWQ;
        e1st[j] = (r * SE_Q + c) * 2;
        e1rd[j] = (r * SA_Q + c) * 2;
        const int gy = y0 - 2 + r, gxb = x0 - 2 + 4 * c;
        const bool yv = (gy >= 0 && gy < YD);
        float4 m;    // stored e1 = max(v, m): valid -> -INF (keep), invalid -> +INF
        m.x = (yv && gxb     >= 0 && gxb     < XD) ? -PINF : PINF;
        m.y = (yv && gxb + 1 >= 0 && gxb + 1 < XD) ? -PINF : PINF;
        m.z = (yv && gxb + 2 >= 0 && gxb + 2 < XD) ? -PINF : PINF;
        m.w = (yv && gxb + 3 >= 0 && gxb + 3 < XD) ? -PINF : PINF;
        e1m[j] = pk4(m);
    }
    // ---- e2 chunks: store into sE2, read from sE1; stored -INF outside volume
    int e2st[2], e2rd[2]; bool e2h[2]; H4 e2m[2];
    #pragma unroll
    for (int j = 0; j < 2; ++j) {
        const int qi = (j == 0) ? tid : tid + (NE2Q - 256);
        e2h[j] = (j == 0) ? true : (tid >= 512 - NE2Q);
        const int r = qi / EWQ, c = qi - r * EWQ;
        e2st[j] = (r * SE_Q + c) * 2;
        e2rd[j] = (r * SE_Q + c) * 2;
        const int gy = y0 - 1 + r, gxb = x0 - 1 + 4 * c;
        const bool yv = (gy >= 0 && gy < YD);
        float4 m;    // stored e2 = min(v, m): valid -> +INF (keep), invalid -> -INF
        m.x = (yv && gxb     >= 0 && gxb     < XD) ? PINF : -PINF;
        m.y = (yv && gxb + 1 >= 0 && gxb + 1 < XD) ? PINF : -PINF;
        m.z = (yv && gxb + 2 >= 0 && gxb + 2 < XD) ? PINF : -PINF;
        m.w = (yv && gxb + 3 >= 0 && gxb + 3 < XD) ? PINF : -PINF;
        e2m[j] = pk4(m);
    }

    // ---- output-quad boundary bools (dilate-on-e1 consumer masks)
    const int gy0 = y0 + ty, gx0 = x0 + 4 * tx;
    const bool rok0 = (gy0 > 0), rok2 = (gy0 < YD - 1);
    const bool lok  = (gx0 > 0), rokx = (gx0 + 4 < XD);

    auto loadq = [&](int zi, int j) -> H4 {
        if (zi < 0 || zi >= ZD || zi > z0 + ZCH + 2 || !a_ok[j]) return HINF4;
        const size_t p = (size_t)zi * PLANE + a_go[j];
        if constexpr (MODE == 0) {
            if (field) {
                const int4 t = *(const int4*)(tgb + p);
                return pk4(make_float4(t.x == 1 ? 1.f : 0.f, t.y == 1 ? 1.f : 0.f,
                                       t.z == 1 ? 1.f : 0.f, t.w == 1 ? 1.f : 0.f));
            } else {
                const float4 a = *(const float4*)(lg0 + p);
                const float4 b = *(const float4*)(lg1 + p);
                return pk4(make_float4(1.f / (1.f + __expf(a.x - b.x)),
                                       1.f / (1.f + __expf(a.y - b.y)),
                                       1.f / (1.f + __expf(a.z - b.z)),
                                       1.f / (1.f + __expf(a.w - b.w))));
            }
        } else {
            return ldp4(inb + p);
        }
    };

    // xy-erode a->e1 at e1 slot j: window starts at element 1 of [A|B]
    auto s1p = [&](int j) -> H4 {
        const hv2* p = sA + e1rd[j];
        const H4 A0 = *(const H4*)p;
        const H4 B0 = *(const H4*)(p + 2);
        const H4 A1 = *(const H4*)(p + SAW2);
        const H4 B1 = *(const H4*)(p + SAW2 + 2);
        const H4 A2 = *(const H4*)(p + 2 * SAW2);
        const H4 B2 = *(const H4*)(p + 2 * SAW2 + 2);
        const hv2 Al = h2min(A0.lo, h2min(A1.lo, A2.lo));   // {a0,a1}
        const hv2 Ah = h2min(A0.hi, h2min(A1.hi, A2.hi));   // {a2,a3}
        const hv2 Bl = h2min(B0.lo, h2min(B1.lo, B2.lo));   // {b0,b1}
        const hv2 Bh = h2min(B0.hi, h2min(B1.hi, B2.hi));   // {b2,b3}
        const hv2 M1 = shf1(Al, Ah);   // {a1,a2}
        const hv2 M2 = shf1(Ah, Bl);   // {a3,b0}
        const hv2 M3 = shf1(Bl, Bh);   // {b1,b2}
        H4 r;
        r.lo = h2min(M1, h2min(Ah, M2));
        r.hi = h2min(M2, h2min(Bl, M3));
        return r;
    };
    // xy-erode e1->e2 at e2 slot j: window starts at element 0 of [E|F]
    auto s2p = [&](int j) -> H4 {
        const hv2* p = sE1 + e2rd[j];
        const H4 E0 = *(const H4*)p;
        const hv2 F0 = p[2];
        const H4 E1 = *(const H4*)(p + SEW2);
        const hv2 F1 = p[SEW2 + 2];
        const H4 E2 = *(const H4*)(p + 2 * SEW2);
        const hv2 F2 = p[2 * SEW2 + 2];
        const hv2 El = h2min(E0.lo, h2min(E1.lo, E2.lo));
        const hv2 Eh = h2min(E0.hi, h2min(E1.hi, E2.hi));
        const hv2 Fl = h2min(F0, h2min(F1, F2));
        const hv2 M1 = shf1(El, Eh);   // {e1,e2}
        const hv2 M2 = shf1(Eh, Fl);   // {e3,f0}
        H4 r;
        r.lo = h2min(El, h2min(M1, Eh));
        r.hi = h2min(Eh, h2min(M2, Fl));
        return r;
    };

    // rings
    H4 s1p2a = HINF4, s1p1a = HINF4, s1p2b = HINF4, s1p1b = HINF4;
    H4 s2p2a = HINF4, s2p1a = HINF4, s2p2b = HINF4, s2p1b = HINF4;
    H4 xm1p2 = HNINF4, xm1p1 = HNINF4;
    H4 xm2p2 = HNINF4, xm2p1 = HNINF4;
    H4 e1w0 = HINF4, e1w1 = HINF4, e2w0 = HINF4, e2w1 = HINF4;
    H4 icp1 = HZ4, icp2 = HZ4, icp3 = HZ4;
    H4 ec1 = HZ4, ec2 = HZ4, ec3 = HZ4;
    H4 e2cp = HZ4;
    H4 dl1r1 = HZ4, dl1r2 = HZ4;

    const size_t eb = (size_t)gy0 * XD + gx0;

    H4 ca0 = loadq(z0 - 3, 0);
    H4 ca1 = loadq(z0 - 3, 1);

    #pragma unroll 1
    for (int s = 0; s < F2STEPS; ++s) {
        const int z = z0 - 3 + s;      // a-plane z stored this step
        // ---------- W phase ----------
        *(H4*)&sA[a_ad[0]] = ca0;
        if (a_h[1]) *(H4*)&sA[a_ad[1]] = ca1;
        if (s >= 1) {                  // e1(z-2), computed last step
            *(H4*)&sE1[e1st[0]] = h4max(e1w0, e1m[0]);
            if (e1h[1]) *(H4*)&sE1[e1st[1]] = h4max(e1w1, e1m[1]);
        }
        if (s >= 2) {                  // e2(z-4), computed last step
            *(H4*)&sE2[e2st[0]] = h4min(e2w0, e2m[0]);
            if (e2h[1]) *(H4*)&sE2[e2st[1]] = h4min(e2w1, e2m[1]);
        }
        __syncthreads();               // B1: planes ready

        // ---------- C phase ----------
        if (s + 1 < F2STEPS) { ca0 = loadq(z + 1, 0); ca1 = loadq(z + 1, 1); }

        // stage 1: e1 candidate for z-1 (held, stored next step)
        {
            const H4 cur = s1p(0);
            e1w0 = h4min(s1p2a, h4min(s1p1a, cur));
            s1p2a = s1p1a; s1p1a = cur;
        }
        if (e1h[1]) {
            const H4 cur = s1p(1);
            e1w1 = h4min(s1p2b, h4min(s1p1b, cur));
            s1p2b = s1p1b; s1p1b = cur;
        }

        const int  ze1 = z - 2;
        const bool ve1 = (s >= 1) && (ze1 >= 0) && (ze1 < ZD);

        // stage 2a: e2 candidate for z-3
        {
            const H4 cur = ve1 ? s2p(0) : HINF4;
            e2w0 = h4min(s2p2a, h4min(s2p1a, cur));
            s2p2a = s2p1a; s2p1a = cur;
        }
        if (e2h[1]) {
            const H4 cur = ve1 ? s2p(1) : HINF4;
            e2w1 = h4min(s2p2b, h4min(s2p1b, cur));
            s2p2b = s2p1b; s2p1b = cur;
        }

        // stage 2b: xy-dilate of e1 at output quad (+ e1 center capture)
        H4 xm1c = HNINF4, e1cc = HZ4;
        if (ve1) {
            const hv2* p = sE1 + ((ty + 1) * SE_Q + tx) * 2;
            H4 A0 = *(const H4*)p;
            H4 Bq0 = *(const H4*)(p + 2);
            const H4 A1 = *(const H4*)(p + SEW2);
            const H4 Bq1 = *(const H4*)(p + SEW2 + 2);
            H4 A2 = *(const H4*)(p + 2 * SEW2);
            H4 Bq2 = *(const H4*)(p + 2 * SEW2 + 2);
            e1cc.lo = A1.hi;            // {a2,a3} = e1 at gx0, gx0+1
            e1cc.hi = Bq1.lo;           // {b0,b1} = e1 at gx0+2, gx0+3
            if (!rok0) { A0 = HNINF4; Bq0 = HNINF4; }
            if (!rok2) { A2 = HNINF4; Bq2 = HNINF4; }
            const hv2 Al = h2max(A0.lo, h2max(A1.lo, A2.lo));
            const hv2 Ah = h2max(A0.hi, h2max(A1.hi, A2.hi));
            const hv2 Bl = h2max(Bq0.lo, h2max(Bq1.lo, Bq2.lo));
            const hv2 Bh = h2max(Bq0.hi, h2max(Bq1.hi, Bq2.hi));
            hv2 M1 = shf1(Al, Ah);      // {a1,a2}; a1 = gx0-1
            const hv2 M2 = shf1(Ah, Bl);
            hv2 M3 = shf1(Bl, Bh);      // {b1,b2}; b2 = gx0+4
            if (!lok)  M1.x = HN1;
            if (!rokx) M3.y = HN1;
            xm1c.lo = h2max(M1, h2max(Ah, M2));
            xm1c.hi = h2max(M2, h2max(Bl, M3));
        }
        const H4 d1v = h4max(xm1p2, h4max(xm1p1, xm1c));   // d1(z-3)
        xm1p2 = xm1p1; xm1p1 = xm1c;

        // stage 3: xy-dilate of e2 at output quad (+ e2 center capture)
        const int  ze2 = z - 4;
        const bool ve2 = (s >= 2) && (ze2 >= 0) && (ze2 < ZD);
        H4 xm2c = HNINF4, e2cc = HZ4;
        if (ve2) {
            const hv2* p = sE2 + (ty * SE_Q + tx) * 2;
            const H4 U0 = *(const H4*)p;
            const hv2 V0 = p[2];
            const H4 U1 = *(const H4*)(p + SEW2);
            const hv2 V1 = p[SEW2 + 2];
            const H4 U2 = *(const H4*)(p + 2 * SEW2);
            const hv2 V2 = p[2 * SEW2 + 2];
            e2cc.lo = shf1(U1.lo, U1.hi);   // {u1,u2} = e2 at gx0, gx0+1
            e2cc.hi = shf1(U1.hi, V1);      // {u3,v0} = e2 at gx0+2, gx0+3
            const hv2 Ul = h2max(U0.lo, h2max(U1.lo, U2.lo));
            const hv2 Uh = h2max(U0.hi, h2max(U1.hi, U2.hi));
            const hv2 Vl = h2max(V0, h2max(V1, V2));
            const hv2 M1 = shf1(Ul, Uh);    // {u1,u2}
            const hv2 M2 = shf1(Uh, Vl);    // {u3,v0}
            xm2c.lo = h2max(Ul, h2max(M1, Uh));
            xm2c.hi = h2max(Uh, h2max(M2, Vl));
        }
        const H4 d2v = h4max(xm2p2, h4max(xm2p1, xm2c));   // d2(z-5)
        xm2p2 = xm2p1; xm2p1 = xm2c;

        const H4 icq = *(const H4*)&sA[((ty + 3) * SA_Q + tx + 1) * 2];  // a(z) center

        // packed deltas: delta_k(z-3) = relu(a_k - d1); delta_{k+1}(z-5) = relu(e1 - d2)
        H4 dl1n, dl2;
        dl1n.lo = h2max(icp3.lo - d1v.lo, Z2);
        dl1n.hi = h2max(icp3.hi - d1v.hi, Z2);
        dl2.lo  = h2max(ec3.lo - d2v.lo, Z2);
        dl2.hi  = h2max(ec3.hi - d2v.hi, Z2);
        const H4 dA = dl1r2;   // delta_k(z-5), fp16-packed ring
        const H4 av = e2cp;    // a_{k+2}(z-5)

        __syncthreads();       // B2: LDS reads done before next W

        // ---------- emission (registers + global only; packed fp16 math) ----------
        if (s >= 8) {
            const int zo = z - 5;  // in [z0, z0+15]
            const size_t idx = (size_t)zo * PLANE + eb;
            H4 sk;
            if constexpr (MODE == 0) {
                sk = dA;                                   // skel = delta0
            } else {
                const H4 s0 = ldp4(skb + idx);
                sk.lo = dA.lo * (ONE2 - s0.lo) + s0.lo;    // v_pk_fma_f16
                sk.hi = dA.hi * (ONE2 - s0.hi) + s0.hi;
            }
            H4 sv;
            sv.lo = dl2.lo * (ONE2 - sk.lo) + sk.lo;
            sv.hi = dl2.hi * (ONE2 - sk.hi) + sk.hi;
            stp4(skb + idx, sv);
            stp4(outb + idx, av);
        }

        // ---------- ring shifts ----------
        dl1r2 = dl1r1; dl1r1 = dl1n;
        icp3 = icp2; icp2 = icp1; icp1 = icq;
        ec3 = ec2; ec2 = ec1; ec1 = e1cc;
        e2cp = e2cc;
    }
}

// ============================ tail kernel (round-4 verified; MODE 2 only) ============================
template <int MODE>   // 2 = last (k=10; in-reg skel update + weighted reduce)
__global__ __launch_bounds__(256)
void fused_kernel(const __half* __restrict__ a_in,
                  __half* __restrict__ a_out,
                  __half* __restrict__ skel,
                  const float* __restrict__ logits,
                  const int* __restrict__ targets,
                  float* __restrict__ sums)
{
    __shared__ __align__(16) hv2 simg[2][IH * SIW * 2];
    __shared__ __align__(16) hv2 sbp[NBQ * 2 + 4];
    __shared__ float red[4][2];

    const int tx = threadIdx.x, ty = threadIdx.y;
    const int tid = ty * 16 + tx;
    const int x0 = (blockIdx.x % 3) * XT, y0 = (blockIdx.x / 3) * YT;
    const int z0 = blockIdx.y * ZCH;
    const int zf = blockIdx.z;
    const int bb = zf & 1, field = zf >> 1;
    const size_t voff = (size_t)zf * VOL;
    const __half* inb  = a_in  + voff;
    __half*       skb  = skel  + voff;
    const float* lg0 = logits + (size_t)(bb * 2) * VOL;
    const float* lg1 = lg0 + VOL;
    const int*   tgb = targets + (size_t)bb * VOL;

    const hv2 INF2  = u2h(0x7C007C00u);
    const hv2 NINF2 = u2h(0xFC00FC00u);
    const hv2 Z2    = u2h(0u);
    const H4 HINF4  = { INF2, INF2 };
    const H4 HNINF4 = { NINF2, NINF2 };
    const H4 HZ4    = { Z2, Z2 };

    // img chunks: chunk1 concentrated (qi = tid + NIMGQ-256, active iff tid >= 512-NIMGQ)
    int im_addr[2], im_goff[2]; bool im_ok[2], im_has[2];
    #pragma unroll
    for (int j = 0; j < 2; ++j) {
        const int qi = (j == 0) ? tid : tid + (NIMGQ - 256);
        im_has[j] = (j == 0) ? true : (tid >= 512 - NIMGQ);
        const int r = qi / IWQ, c = qi - r * IWQ;
        const int gy = y0 - 2 + r, gxb = x0 - 4 + 4 * c;
        im_ok[j]  = im_has[j] && gy >= 0 && gy < YD && gxb >= 0 && gxb < XD;
        im_goff[j] = gy * XD + gxb;
        im_addr[j] = (r * SIW + c) * 2;
    }
    int bqi[2], brow[2], bcol[2]; bool bhas[2]; H4 bmask[2];
    #pragma unroll
    for (int j = 0; j < 2; ++j) {
        const int qi = (j == 0) ? tid : tid + (NBQ - 256);
        bqi[j] = qi;
        bhas[j] = (j == 0) ? true : (tid >= 512 - NBQ);
        const int r = qi / BWQ, c = qi - r * BWQ;
        brow[j] = r; bcol[j] = c;
        const int gy = y0 - 1 + r, gxb = x0 - 1 + 4 * c;
        const bool yv = (gy >= 0 && gy < YD);
        float4 m;
        m.x = (yv && gxb     >= 0 && gxb     < XD) ? PINF : -PINF;
        m.y = (yv && gxb + 1 >= 0 && gxb + 1 < XD) ? PINF : -PINF;
        m.z = (yv && gxb + 2 >= 0 && gxb + 2 < XD) ? PINF : -PINF;
        m.w = (yv && gxb + 3 >= 0 && gxb + 3 < XD) ? PINF : -PINF;
        bmask[j] = pk4(m);
    }

    auto loadq = [&](int zi, int j) -> H4 {
        if (zi < 0 || zi >= ZD || !im_ok[j]) return HINF4;
        const size_t p = (size_t)zi * PLANE + im_goff[j];
        return ldp4(inb + p);
    };

    auto s1_of = [&](const hv2* sp, int j) -> H4 {
        const hv2* p = sp + (brow[j] * SIW + bcol[j]) * 2;
        const hv2 A0 = p[1];
        const hv2 A1 = p[SIW * 2 + 1];
        const hv2 A2 = p[SIW * 4 + 1];
        const H4 B0 = *(const H4*)(p + 2);
        const H4 B1 = *(const H4*)(p + SIW * 2 + 2);
        const H4 B2 = *(const H4*)(p + SIW * 4 + 2);
        const hv2 Ah = h2min(A0, h2min(A1, A2));
        const hv2 Bl = h2min(B0.lo, h2min(B1.lo, B2.lo));
        const hv2 Bh = h2min(B0.hi, h2min(B1.hi, B2.hi));
        const hv2 S1 = shf1(Ah, Bl);
        const hv2 S2 = shf1(Bl, Bh);
        H4 r;
        r.lo = h2min(Ah, h2min(S1, Bl));
        r.hi = h2min(Bl, h2min(S2, Bh));
        return r;
    };

    H4 p2a = HINF4, p1a = HINF4;
    H4 p2b = HINF4, p1b = HINF4;
    H4 s2p1 = HNINF4, s2p2 = HNINF4;
    H4 icp1 = HZ4, icp2 = HZ4;
    float sd = 0.f, ss = 0.f;

    H4 ca0 = loadq(z0 - 2, 0);
    H4 ca1 = loadq(z0 - 2, 1);

    #pragma unroll 2
    for (int s = 0; s < TSTEPS; ++s) {
        const int zi = z0 - 2 + s;
        hv2* sp = simg[s & 1];
        *(H4*)&sp[im_addr[0]] = ca0;
        if (im_has[1]) *(H4*)&sp[im_addr[1]] = ca1;
        if (s + 1 < TSTEPS) { ca0 = loadq(zi + 1, 0); ca1 = loadq(zi + 1, 1); }
        __syncthreads();
        const int zb = zi - 1;
        const bool zbv = (s >= 2) && (zb >= 0) && (zb < ZD);
        {
            const H4 cur = s1_of(sp, 0);
            if (zbv) {
                const H4 b = h4min(h4min(p2a, p1a), cur);
                *(H4*)&sbp[2 * bqi[0]] = h4min(b, bmask[0]);
            }
            p2a = p1a; p1a = cur;
        }
        if (bhas[1]) {
            const H4 cur = s1_of(sp, 1);
            if (zbv) {
                const H4 b = h4min(h4min(p2b, p1b), cur);
                *(H4*)&sbp[2 * bqi[1]] = h4min(b, bmask[1]);
            }
            p2b = p1b; p1b = cur;
        }
        const H4 icq = *(const H4*)&sp[((ty + 2) * SIW + tx + 1) * 2];
        __syncthreads();
        H4 s2n = HNINF4;
        if (zbv) {
            const hv2* p = sbp + (ty * BWQ + tx) * 2;
            const H4 U0 = *(const H4*)p;
            const H4 U1 = *(const H4*)(p + BWQ * 2);
            const H4 U2 = *(const H4*)(p + BWQ * 4);
            const hv2 V0 = p[2];
            const hv2 V1 = p[BWQ * 2 + 2];
            const hv2 V2 = p[BWQ * 4 + 2];
            const hv2 Ul = h2max(U0.lo, h2max(U1.lo, U2.lo));
            const hv2 Uh = h2max(U0.hi, h2max(U1.hi, U2.hi));
            const hv2 Vl = h2max(V0, h2max(V1, V2));
            const hv2 S1 = shf1(Ul, Uh);
            const hv2 S2 = shf1(Uh, Vl);
            s2n.lo = h2max(Ul, h2max(S1, Uh));
            s2n.hi = h2max(Uh, h2max(S2, Vl));
        }
        if (s >= 4) {
            const int zo = zi - 2;
            const H4 d = h4max(s2p2, h4max(s2p1, s2n));
            float4 dl;
            dl.x = fmaxf((float)icp2.lo.x - (float)d.lo.x, 0.f);
            dl.y = fmaxf((float)icp2.lo.y - (float)d.lo.y, 0.f);
            dl.z = fmaxf((float)icp2.hi.x - (float)d.hi.x, 0.f);
            dl.w = fmaxf((float)icp2.hi.y - (float)d.hi.y, 0.f);
            const size_t idx = (size_t)zo * PLANE + (size_t)(y0 + ty) * XD + (x0 + 4 * tx);
            const H4 sk = ldp4(skb + idx);
            const float s0x = (float)sk.lo.x, s0y = (float)sk.lo.y;
            const float s0z = (float)sk.hi.x, s0w = (float)sk.hi.y;
            float4 sv;
            sv.x = s0x + dl.x * (1.f - s0x);
            sv.y = s0y + dl.y * (1.f - s0y);
            sv.z = s0z + dl.z * (1.f - s0z);
            sv.w = s0w + dl.w * (1.f - s0w);
            float4 w;
            if (field) {
                const float4 a = *(const float4*)(lg0 + idx);
                const float4 b = *(const float4*)(lg1 + idx);
                w = make_float4(1.f / (1.f + __expf(a.x - b.x)),
                                1.f / (1.f + __expf(a.y - b.y)),
                                1.f / (1.f + __expf(a.z - b.z)),
                                1.f / (1.f + __expf(a.w - b.w)));
            } else {
                const int4 t = *(const int4*)(tgb + idx);
                w = make_float4(t.x == 1 ? 1.f : 0.f, t.y == 1 ? 1.f : 0.f,
                                t.z == 1 ? 1.f : 0.f, t.w == 1 ? 1.f : 0.f);
            }
            sd += sv.x * w.x + sv.y * w.y + sv.z * w.z + sv.w * w.w;
            ss += sv.x + sv.y + sv.z + sv.w;
        }
        s2p2 = s2p1; s2p1 = s2n;
        icp2 = icp1; icp1 = icq;
    }

    if constexpr (MODE == 2) {
        #pragma unroll
        for (int o = 32; o; o >>= 1) {
            sd += __shfl_down(sd, o, 64);
            ss += __shfl_down(ss, o, 64);
        }
        const int w = tid >> 6;
        if ((tid & 63) == 0) { red[w][0] = sd; red[w][1] = ss; }
        __syncthreads();
        if (tid == 0) {
            float a = 0.f, b = 0.f;
            #pragma unroll
            for (int i = 0; i < 4; ++i) { a += red[i][0]; b += red[i][1]; }
            atomicAdd(&sums[2 * field + 0], a);
            atomicAdd(&sums[2 * field + 1], b);
        }
    }
}

__global__ void final_kernel(const float* __restrict__ sums, float* __restrict__ out)
{
    float tprec = (sums[0] + 1.f) / (sums[1] + 1.f);
    float tsens = (sums[2] + 1.f) / (sums[3] + 1.f);
    float cl = 2.f * tprec * tsens / (tprec + tsens + 1e-7f);
    out[0] = 1.f - cl;
}

extern "C" void kernel_launch(void* const* d_in, const int* in_sizes, int n_in,
                              void* d_out, int out_size, void* d_ws, size_t ws_size,
                              hipStream_t stream)
{
    const float* logits  = (const float*)d_in[0];
    const int*   targets = (const int*)d_in[1];
    float* out  = (float*)d_out;

    float*  sums = (float*)d_ws;
    __half* A    = (__half*)(sums + 16);
    __half* B    = A + NVOL4;
    __half* SK   = B + NVOL4;

    hipMemsetAsync(sums, 0, 16 * sizeof(float), stream);

    dim3 g(3 * (YD / YT), ZD / ZCH, 4);    // (36, 12, 4) = 1728 blocks
    dim3 blk(16, 16, 1);

    // pairs (0,1),(2,3),(4,5),(6,7),(8,9): 5 fused dispatches
    fused2p_kernel<0><<<g, blk, 0, stream>>>(A, A, SK, logits, targets);  // a2 -> A
    fused2p_kernel<1><<<g, blk, 0, stream>>>(A, B, SK, logits, targets);  // a4 -> B
    fused2p_kernel<1><<<g, blk, 0, stream>>>(B, A, SK, logits, targets);  // a6 -> A
    fused2p_kernel<1><<<g, blk, 0, stream>>>(A, B, SK, logits, targets);  // a8 -> B
    fused2p_kernel<1><<<g, blk, 0, stream>>>(B, A, SK, logits, targets);  // a10 -> A
    // k = 10: read a10 (in A), in-reg skel update + weighted reduce
    fused_kernel<2><<<g, blk, 0, stream>>>(A, B, SK, logits, targets, sums);

    final_kernel<<<1, 1, 0, stream>>>(sums, out);
}

// Round 12
// 840.496 us; speedup vs baseline: 1.1162x; 1.0138x over previous
//
#include <hip/hip_runtime.h>
#include <hip/hip_fp16.h>

// CLDice loss, round 14 (resubmit; round-11 bench was an infra failure, no signal
// -- 4th env failure this session; all prior resubmits of unchanged source passed).
// Round-13 base (852us verified: fused-2 packed, wave-concentrated chunks,
// packed-fp16 emission) + FZCH=32 z-chunks for the fused kernel: 40 steps per
// 32 output planes (1.25 steps/plane) vs 24/16 (1.5) => 17% fewer total steps
// at identical per-step code. Grid 1728->864 blocks (3.375/CU; imbalance claws
// back ~half in the issue-bound model).
// Session law: only deleting issued work moves this kernel (982->919->852).
// Tail (k=10) kernel untouched (ZCH=16 geometry, verified).

#define ZD 192
#define YD 192
#define XD 192
constexpr int PLANE = YD * XD;
constexpr int VOL   = ZD * PLANE;
constexpr int NVOL4 = 4 * VOL;

constexpr int XT = 64, YT = 16, ZCH = 16;     // tail z-chunk
constexpr int FZCH = 32;                      // fused z-chunk (this round's change)

// ---- fused-2 geometry ----
constexpr int AWQ = 18, SA_Q = 19, AH = 22;   // a: rows y0-3..y0+18, quads x0-4+4c
constexpr int NAQ = AH * AWQ;                 // 396 -> extras 140, thresh 116
constexpr int EWQ = 17, SE_Q = 17;            // e1/e2: 17 real quads, odd stride
constexpr int E1H = 20;                       // e1: rows y0-2..y0+17, quads x0-2+4c
constexpr int NE1Q = E1H * EWQ;               // 340 -> extras 84, thresh 172
constexpr int E2H = 18;                       // e2: rows y0-1..y0+16, quads x0-1+4c
constexpr int NE2Q = E2H * EWQ;               // 306 -> extras 50, thresh 206
constexpr int F2STEPS = FZCH + 8;             // 40; emission at s>=8, zo=z-5
constexpr int SAW2 = SA_Q * 2;                // hv2 row strides
constexpr int SEW2 = SE_Q * 2;

// ---- tail (single-iteration, round-4 verified) geometry ----
constexpr int IWQ = 18, SIW = 19;
constexpr int IH  = 20;
constexpr int NIMGQ = IH * IWQ;               // 360 -> extras 104, thresh 152
constexpr int BWQ = 17, BH = 18;
constexpr int NBQ  = BH * BWQ;                // 306 -> extras 50, thresh 206
constexpr int TSTEPS = ZCH + 4;               // 20
#define PINF __builtin_inff()

typedef _Float16 hv2 __attribute__((ext_vector_type(2)));
struct __align__(8) H4 { hv2 lo, hi; };       // 4 halfs = 8 B = one "quad"

__device__ __forceinline__ unsigned h2u(hv2 h) { return __builtin_bit_cast(unsigned, h); }
__device__ __forceinline__ hv2 u2h(unsigned u) { return __builtin_bit_cast(hv2, u); }

__device__ __forceinline__ hv2 h2min(hv2 a, hv2 b) {
#if __has_builtin(__builtin_elementwise_min)
    return __builtin_elementwise_min(a, b);
#else
    unsigned r, ua = h2u(a), ub = h2u(b);
    asm("v_pk_min_f16 %0, %1, %2" : "=v"(r) : "v"(ua), "v"(ub));
    return u2h(r);
#endif
}
__device__ __forceinline__ hv2 h2max(hv2 a, hv2 b) {
#if __has_builtin(__builtin_elementwise_max)
    return __builtin_elementwise_max(a, b);
#else
    unsigned r, ua = h2u(a), ub = h2u(b);
    asm("v_pk_max_f16 %0, %1, %2" : "=v"(r) : "v"(ua), "v"(ub));
    return u2h(r);
#endif
}
// {c.y, n.x}: one-element left shift across a packed pair boundary
__device__ __forceinline__ hv2 shf1(hv2 c, hv2 n) {
    return u2h(__builtin_amdgcn_alignbit(h2u(n), h2u(c), 16));
}
__device__ __forceinline__ H4 h4min(H4 a, H4 b) { H4 r; r.lo = h2min(a.lo, b.lo); r.hi = h2min(a.hi, b.hi); return r; }
__device__ __forceinline__ H4 h4max(H4 a, H4 b) { H4 r; r.lo = h2max(a.lo, b.lo); r.hi = h2max(a.hi, b.hi); return r; }
__device__ __forceinline__ H4 pk4(float4 v) {
    H4 r;
    r.lo.x = (_Float16)v.x; r.lo.y = (_Float16)v.y;
    r.hi.x = (_Float16)v.z; r.hi.y = (_Float16)v.w;
    return r;
}
__device__ __forceinline__ H4 ldp4(const __half* p) {
    const uint2 v = *(const uint2*)p;
    H4 r; r.lo = u2h(v.x); r.hi = u2h(v.y); return r;
}
__device__ __forceinline__ void stp4(__half* p, H4 v) {
    uint2 u; u.x = h2u(v.lo); u.y = h2u(v.hi);
    *(uint2*)p = u;
}
__device__ __forceinline__ void sth4(__half* p, float4 v) { stp4(p, pk4(v)); }

// ============================ fused-2 packed kernel ============================
// MODE 0: first pair (k=0,1): a0 built inline from logits/targets, skel = delta0 then delta1.
// MODE 1: mid pair: read a_k + skel, write a_{k+2} + skel.
template <int MODE>
__global__ __launch_bounds__(256)
void fused2p_kernel(const __half* __restrict__ a_in,
                    __half* __restrict__ a_out,
                    __half* __restrict__ skel,
                    const float* __restrict__ logits,
                    const int* __restrict__ targets)
{
    __shared__ __align__(16) hv2 sA [AH  * SA_Q * 2];       // 836 hv2 = 3344 B
    __shared__ __align__(16) hv2 sE1[E1H * SE_Q * 2 + 2];   // 682 hv2 (+2 edge pad)
    __shared__ __align__(16) hv2 sE2[E2H * SE_Q * 2];       // 612 hv2

    const int tx = threadIdx.x, ty = threadIdx.y;   // (16,16)
    const int tid = ty * 16 + tx;
    const int x0 = (blockIdx.x % 3) * XT, y0 = (blockIdx.x / 3) * YT;
    const int z0 = blockIdx.y * FZCH;
    const int zf = blockIdx.z;                      // 0..3
    const int bb = zf & 1, field = zf >> 1;
    const size_t voff = (size_t)zf * VOL;
    const __half* inb  = a_in  + voff;
    __half*       outb = a_out + voff;
    __half*       skb  = skel  + voff;
    const float* lg0 = logits + (size_t)(bb * 2) * VOL;
    const float* lg1 = lg0 + VOL;
    const int*   tgb = targets + (size_t)bb * VOL;

    const hv2 INF2  = u2h(0x7C007C00u);
    const hv2 NINF2 = u2h(0xFC00FC00u);
    const hv2 Z2    = u2h(0u);
    const hv2 ONE2  = u2h(0x3C003C00u);
    const H4 HINF4  = { INF2, INF2 };
    const H4 HNINF4 = { NINF2, NINF2 };
    const H4 HZ4    = { Z2, Z2 };
    const _Float16 HN1 = (_Float16)(-PINF);

    // ---- a-plane chunks: qi -> (r=qi/18, c=qi%18); covers (y0-3+r, x0-4+4c)
    // chunk1 concentrated: qi = tid + (NAQ-256), active iff tid >= 512-NAQ
    int a_ad[2], a_go[2]; bool a_ok[2], a_h[2];
    #pragma unroll
    for (int j = 0; j < 2; ++j) {
        const int qi = (j == 0) ? tid : tid + (NAQ - 256);
        a_h[j] = (j == 0) ? true : (tid >= 512 - NAQ);
        const int r = qi / AWQ, c = qi - r * AWQ;
        const int gy = y0 - 3 + r, gxb = x0 - 4 + 4 * c;
        a_ok[j] = a_h[j] && gy >= 0 && gy < YD && gxb >= 0 && gxb < XD;
        a_go[j] = gy * XD + gxb;
        a_ad[j] = (r * SA_Q + c) * 2;
    }
    // ---- e1 chunks: store into sE1, read from sA; stored +INF outside volume
    int e1st[2], e1rd[2]; bool e1h[2]; H4 e1m[2];
    #pragma unroll
    for (int j = 0; j < 2; ++j) {
        const int qi = (j == 0) ? tid : tid + (NE1Q - 256);
        e1h[j] = (j == 0) ? true : (tid >= 512 - NE1Q);
        const int r = qi / EWQ, c = qi - r * EWQ;
        e1st[j] = (r * SE_Q + c) * 2;
        e1rd[j] = (r * SA_Q + c) * 2;
        const int gy = y0 - 2 + r, gxb = x0 - 2 + 4 * c;
        const bool yv = (gy >= 0 && gy < YD);
        float4 m;    // stored e1 = max(v, m): valid -> -INF (keep), invalid -> +INF
        m.x = (yv && gxb     >= 0 && gxb     < XD) ? -PINF : PINF;
        m.y = (yv && gxb + 1 >= 0 && gxb + 1 < XD) ? -PINF : PINF;
        m.z = (yv && gxb + 2 >= 0 && gxb + 2 < XD) ? -PINF : PINF;
        m.w = (yv && gxb + 3 >= 0 && gxb + 3 < XD) ? -PINF : PINF;
        e1m[j] = pk4(m);
    }
    // ---- e2 chunks: store into sE2, read from sE1; stored -INF outside volume
    int e2st[2], e2rd[2]; bool e2h[2]; H4 e2m[2];
    #pragma unroll
    for (int j = 0; j < 2; ++j) {
        const int qi = (j == 0) ? tid : tid + (NE2Q - 256);
        e2h[j] = (j == 0) ? true : (tid >= 512 - NE2Q);
        const int r = qi / EWQ, c = qi - r * EWQ;
        e2st[j] = (r * SE_Q + c) * 2;
        e2rd[j] = (r * SE_Q + c) * 2;
        const int gy = y0 - 1 + r, gxb = x0 - 1 + 4 * c;
        const bool yv = (gy >= 0 && gy < YD);
        float4 m;    // stored e2 = min(v, m): valid -> +INF (keep), invalid -> -INF
        m.x = (yv && gxb     >= 0 && gxb     < XD) ? PINF : -PINF;
        m.y = (yv && gxb + 1 >= 0 && gxb + 1 < XD) ? PINF : -PINF;
        m.z = (yv && gxb + 2 >= 0 && gxb + 2 < XD) ? PINF : -PINF;
        m.w = (yv && gxb + 3 >= 0 && gxb + 3 < XD) ? PINF : -PINF;
        e2m[j] = pk4(m);
    }

    // ---- output-quad boundary bools (dilate-on-e1 consumer masks)
    const int gy0 = y0 + ty, gx0 = x0 + 4 * tx;
    const bool rok0 = (gy0 > 0), rok2 = (gy0 < YD - 1);
    const bool lok  = (gx0 > 0), rokx = (gx0 + 4 < XD);

    auto loadq = [&](int zi, int j) -> H4 {
        if (zi < 0 || zi >= ZD || zi > z0 + FZCH + 2 || !a_ok[j]) return HINF4;
        const size_t p = (size_t)zi * PLANE + a_go[j];
        if constexpr (MODE == 0) {
            if (field) {
                const int4 t = *(const int4*)(tgb + p);
                return pk4(make_float4(t.x == 1 ? 1.f : 0.f, t.y == 1 ? 1.f : 0.f,
                                       t.z == 1 ? 1.f : 0.f, t.w == 1 ? 1.f : 0.f));
            } else {
                const float4 a = *(const float4*)(lg0 + p);
                const float4 b = *(const float4*)(lg1 + p);
                return pk4(make_float4(1.f / (1.f + __expf(a.x - b.x)),
                                       1.f / (1.f + __expf(a.y - b.y)),
                                       1.f / (1.f + __expf(a.z - b.z)),
                                       1.f / (1.f + __expf(a.w - b.w))));
            }
        } else {
            return ldp4(inb + p);
        }
    };

    // xy-erode a->e1 at e1 slot j: window starts at element 1 of [A|B]
    auto s1p = [&](int j) -> H4 {
        const hv2* p = sA + e1rd[j];
        const H4 A0 = *(const H4*)p;
        const H4 B0 = *(const H4*)(p + 2);
        const H4 A1 = *(const H4*)(p + SAW2);
        const H4 B1 = *(const H4*)(p + SAW2 + 2);
        const H4 A2 = *(const H4*)(p + 2 * SAW2);
        const H4 B2 = *(const H4*)(p + 2 * SAW2 + 2);
        const hv2 Al = h2min(A0.lo, h2min(A1.lo, A2.lo));   // {a0,a1}
        const hv2 Ah = h2min(A0.hi, h2min(A1.hi, A2.hi));   // {a2,a3}
        const hv2 Bl = h2min(B0.lo, h2min(B1.lo, B2.lo));   // {b0,b1}
        const hv2 Bh = h2min(B0.hi, h2min(B1.hi, B2.hi));   // {b2,b3}
        const hv2 M1 = shf1(Al, Ah);   // {a1,a2}
        const hv2 M2 = shf1(Ah, Bl);   // {a3,b0}
        const hv2 M3 = shf1(Bl, Bh);   // {b1,b2}
        H4 r;
        r.lo = h2min(M1, h2min(Ah, M2));
        r.hi = h2min(M2, h2min(Bl, M3));
        return r;
    };
    // xy-erode e1->e2 at e2 slot j: window starts at element 0 of [E|F]
    auto s2p = [&](int j) -> H4 {
        const hv2* p = sE1 + e2rd[j];
        const H4 E0 = *(const H4*)p;
        const hv2 F0 = p[2];
        const H4 E1 = *(const H4*)(p + SEW2);
        const hv2 F1 = p[SEW2 + 2];
        const H4 E2 = *(const H4*)(p + 2 * SEW2);
        const hv2 F2 = p[2 * SEW2 + 2];
        const hv2 El = h2min(E0.lo, h2min(E1.lo, E2.lo));
        const hv2 Eh = h2min(E0.hi, h2min(E1.hi, E2.hi));
        const hv2 Fl = h2min(F0, h2min(F1, F2));
        const hv2 M1 = shf1(El, Eh);   // {e1,e2}
        const hv2 M2 = shf1(Eh, Fl);   // {e3,f0}
        H4 r;
        r.lo = h2min(El, h2min(M1, Eh));
        r.hi = h2min(Eh, h2min(M2, Fl));
        return r;
    };

    // rings
    H4 s1p2a = HINF4, s1p1a = HINF4, s1p2b = HINF4, s1p1b = HINF4;
    H4 s2p2a = HINF4, s2p1a = HINF4, s2p2b = HINF4, s2p1b = HINF4;
    H4 xm1p2 = HNINF4, xm1p1 = HNINF4;
    H4 xm2p2 = HNINF4, xm2p1 = HNINF4;
    H4 e1w0 = HINF4, e1w1 = HINF4, e2w0 = HINF4, e2w1 = HINF4;
    H4 icp1 = HZ4, icp2 = HZ4, icp3 = HZ4;
    H4 ec1 = HZ4, ec2 = HZ4, ec3 = HZ4;
    H4 e2cp = HZ4;
    H4 dl1r1 = HZ4, dl1r2 = HZ4;

    const size_t eb = (size_t)gy0 * XD + gx0;

    H4 ca0 = loadq(z0 - 3, 0);
    H4 ca1 = loadq(z0 - 3, 1);

    #pragma unroll 1
    for (int s = 0; s < F2STEPS; ++s) {
        const int z = z0 - 3 + s;      // a-plane z stored this step
        // ---------- W phase ----------
        *(H4*)&sA[a_ad[0]] = ca0;
        if (a_h[1]) *(H4*)&sA[a_ad[1]] = ca1;
        if (s >= 1) {                  // e1(z-2), computed last step
            *(H4*)&sE1[e1st[0]] = h4max(e1w0, e1m[0]);
            if (e1h[1]) *(H4*)&sE1[e1st[1]] = h4max(e1w1, e1m[1]);
        }
        if (s >= 2) {                  // e2(z-4), computed last step
            *(H4*)&sE2[e2st[0]] = h4min(e2w0, e2m[0]);
            if (e2h[1]) *(H4*)&sE2[e2st[1]] = h4min(e2w1, e2m[1]);
        }
        __syncthreads();               // B1: planes ready

        // ---------- C phase ----------
        if (s + 1 < F2STEPS) { ca0 = loadq(z + 1, 0); ca1 = loadq(z + 1, 1); }

        // stage 1: e1 candidate for z-1 (held, stored next step)
        {
            const H4 cur = s1p(0);
            e1w0 = h4min(s1p2a, h4min(s1p1a, cur));
            s1p2a = s1p1a; s1p1a = cur;
        }
        if (e1h[1]) {
            const H4 cur = s1p(1);
            e1w1 = h4min(s1p2b, h4min(s1p1b, cur));
            s1p2b = s1p1b; s1p1b = cur;
        }

        const int  ze1 = z - 2;
        const bool ve1 = (s >= 1) && (ze1 >= 0) && (ze1 < ZD);

        // stage 2a: e2 candidate for z-3
        {
            const H4 cur = ve1 ? s2p(0) : HINF4;
            e2w0 = h4min(s2p2a, h4min(s2p1a, cur));
            s2p2a = s2p1a; s2p1a = cur;
        }
        if (e2h[1]) {
            const H4 cur = ve1 ? s2p(1) : HINF4;
            e2w1 = h4min(s2p2b, h4min(s2p1b, cur));
            s2p2b = s2p1b; s2p1b = cur;
        }

        // stage 2b: xy-dilate of e1 at output quad (+ e1 center capture)
        H4 xm1c = HNINF4, e1cc = HZ4;
        if (ve1) {
            const hv2* p = sE1 + ((ty + 1) * SE_Q + tx) * 2;
            H4 A0 = *(const H4*)p;
            H4 Bq0 = *(const H4*)(p + 2);
            const H4 A1 = *(const H4*)(p + SEW2);
            const H4 Bq1 = *(const H4*)(p + SEW2 + 2);
            H4 A2 = *(const H4*)(p + 2 * SEW2);
            H4 Bq2 = *(const H4*)(p + 2 * SEW2 + 2);
            e1cc.lo = A1.hi;            // {a2,a3} = e1 at gx0, gx0+1
            e1cc.hi = Bq1.lo;           // {b0,b1} = e1 at gx0+2, gx0+3
            if (!rok0) { A0 = HNINF4; Bq0 = HNINF4; }
            if (!rok2) { A2 = HNINF4; Bq2 = HNINF4; }
            const hv2 Al = h2max(A0.lo, h2max(A1.lo, A2.lo));
            const hv2 Ah = h2max(A0.hi, h2max(A1.hi, A2.hi));
            const hv2 Bl = h2max(Bq0.lo, h2max(Bq1.lo, Bq2.lo));
            const hv2 Bh = h2max(Bq0.hi, h2max(Bq1.hi, Bq2.hi));
            hv2 M1 = shf1(Al, Ah);      // {a1,a2}; a1 = gx0-1
            const hv2 M2 = shf1(Ah, Bl);
            hv2 M3 = shf1(Bl, Bh);      // {b1,b2}; b2 = gx0+4
            if (!lok)  M1.x = HN1;
            if (!rokx) M3.y = HN1;
            xm1c.lo = h2max(M1, h2max(Ah, M2));
            xm1c.hi = h2max(M2, h2max(Bl, M3));
        }
        const H4 d1v = h4max(xm1p2, h4max(xm1p1, xm1c));   // d1(z-3)
        xm1p2 = xm1p1; xm1p1 = xm1c;

        // stage 3: xy-dilate of e2 at output quad (+ e2 center capture)
        const int  ze2 = z - 4;
        const bool ve2 = (s >= 2) && (ze2 >= 0) && (ze2 < ZD);
        H4 xm2c = HNINF4, e2cc = HZ4;
        if (ve2) {
            const hv2* p = sE2 + (ty * SE_Q + tx) * 2;
            const H4 U0 = *(const H4*)p;
            const hv2 V0 = p[2];
            const H4 U1 = *(const H4*)(p + SEW2);
            const hv2 V1 = p[SEW2 + 2];
            const H4 U2 = *(const H4*)(p + 2 * SEW2);
            const hv2 V2 = p[2 * SEW2 + 2];
            e2cc.lo = shf1(U1.lo, U1.hi);   // {u1,u2} = e2 at gx0, gx0+1
            e2cc.hi = shf1(U1.hi, V1);      // {u3,v0} = e2 at gx0+2, gx0+3
            const hv2 Ul = h2max(U0.lo, h2max(U1.lo, U2.lo));
            const hv2 Uh = h2max(U0.hi, h2max(U1.hi, U2.hi));
            const hv2 Vl = h2max(V0, h2max(V1, V2));
            const hv2 M1 = shf1(Ul, Uh);    // {u1,u2}
            const hv2 M2 = shf1(Uh, Vl);    // {u3,v0}
            xm2c.lo = h2max(Ul, h2max(M1, Uh));
            xm2c.hi = h2max(Uh, h2max(M2, Vl));
        }
        const H4 d2v = h4max(xm2p2, h4max(xm2p1, xm2c));   // d2(z-5)
        xm2p2 = xm2p1; xm2p1 = xm2c;

        const H4 icq = *(const H4*)&sA[((ty + 3) * SA_Q + tx + 1) * 2];  // a(z) center

        // packed deltas: delta_k(z-3) = relu(a_k - d1); delta_{k+1}(z-5) = relu(e1 - d2)
        H4 dl1n, dl2;
        dl1n.lo = h2max(icp3.lo - d1v.lo, Z2);
        dl1n.hi = h2max(icp3.hi - d1v.hi, Z2);
        dl2.lo  = h2max(ec3.lo - d2v.lo, Z2);
        dl2.hi  = h2max(ec3.hi - d2v.hi, Z2);
        const H4 dA = dl1r2;   // delta_k(z-5), fp16-packed ring
        const H4 av = e2cp;    // a_{k+2}(z-5)

        __syncthreads();       // B2: LDS reads done before next W

        // ---------- emission (registers + global only; packed fp16 math) ----------
        if (s >= 8) {
            const int zo = z - 5;  // in [z0, z0+FZCH-1]
            const size_t idx = (size_t)zo * PLANE + eb;
            H4 sk;
            if constexpr (MODE == 0) {
                sk = dA;                                   // skel = delta0
            } else {
                const H4 s0 = ldp4(skb + idx);
                sk.lo = dA.lo * (ONE2 - s0.lo) + s0.lo;    // v_pk_fma_f16
                sk.hi = dA.hi * (ONE2 - s0.hi) + s0.hi;
            }
            H4 sv;
            sv.lo = dl2.lo * (ONE2 - sk.lo) + sk.lo;
            sv.hi = dl2.hi * (ONE2 - sk.hi) + sk.hi;
            stp4(skb + idx, sv);
            stp4(outb + idx, av);
        }

        // ---------- ring shifts ----------
        dl1r2 = dl1r1; dl1r1 = dl1n;
        icp3 = icp2; icp2 = icp1; icp1 = icq;
        ec3 = ec2; ec2 = ec1; ec1 = e1cc;
        e2cp = e2cc;
    }
}

// ============================ tail kernel (round-4 verified; MODE 2 only) ============================
template <int MODE>   // 2 = last (k=10; in-reg skel update + weighted reduce)
__global__ __launch_bounds__(256)
void fused_kernel(const __half* __restrict__ a_in,
                  __half* __restrict__ a_out,
                  __half* __restrict__ skel,
                  const float* __restrict__ logits,
                  const int* __restrict__ targets,
                  float* __restrict__ sums)
{
    __shared__ __align__(16) hv2 simg[2][IH * SIW * 2];
    __shared__ __align__(16) hv2 sbp[NBQ * 2 + 4];
    __shared__ float red[4][2];

    const int tx = threadIdx.x, ty = threadIdx.y;
    const int tid = ty * 16 + tx;
    const int x0 = (blockIdx.x % 3) * XT, y0 = (blockIdx.x / 3) * YT;
    const int z0 = blockIdx.y * ZCH;
    const int zf = blockIdx.z;
    const int bb = zf & 1, field = zf >> 1;
    const size_t voff = (size_t)zf * VOL;
    const __half* inb  = a_in  + voff;
    __half*       skb  = skel  + voff;
    const float* lg0 = logits + (size_t)(bb * 2) * VOL;
    const float* lg1 = lg0 + VOL;
    const int*   tgb = targets + (size_t)bb * VOL;

    const hv2 INF2  = u2h(0x7C007C00u);
    const hv2 NINF2 = u2h(0xFC00FC00u);
    const hv2 Z2    = u2h(0u);
    const H4 HINF4  = { INF2, INF2 };
    const H4 HNINF4 = { NINF2, NINF2 };
    const H4 HZ4    = { Z2, Z2 };

    // img chunks: chunk1 concentrated (qi = tid + NIMGQ-256, active iff tid >= 512-NIMGQ)
    int im_addr[2], im_goff[2]; bool im_ok[2], im_has[2];
    #pragma unroll
    for (int j = 0; j < 2; ++j) {
        const int qi = (j == 0) ? tid : tid + (NIMGQ - 256);
        im_has[j] = (j == 0) ? true : (tid >= 512 - NIMGQ);
        const int r = qi / IWQ, c = qi - r * IWQ;
        const int gy = y0 - 2 + r, gxb = x0 - 4 + 4 * c;
        im_ok[j]  = im_has[j] && gy >= 0 && gy < YD && gxb >= 0 && gxb < XD;
        im_goff[j] = gy * XD + gxb;
        im_addr[j] = (r * SIW + c) * 2;
    }
    int bqi[2], brow[2], bcol[2]; bool bhas[2]; H4 bmask[2];
    #pragma unroll
    for (int j = 0; j < 2; ++j) {
        const int qi = (j == 0) ? tid : tid + (NBQ - 256);
        bqi[j] = qi;
        bhas[j] = (j == 0) ? true : (tid >= 512 - NBQ);
        const int r = qi / BWQ, c = qi - r * BWQ;
        brow[j] = r; bcol[j] = c;
        const int gy = y0 - 1 + r, gxb = x0 - 1 + 4 * c;
        const bool yv = (gy >= 0 && gy < YD);
        float4 m;
        m.x = (yv && gxb     >= 0 && gxb     < XD) ? PINF : -PINF;
        m.y = (yv && gxb + 1 >= 0 && gxb + 1 < XD) ? PINF : -PINF;
        m.z = (yv && gxb + 2 >= 0 && gxb + 2 < XD) ? PINF : -PINF;
        m.w = (yv && gxb + 3 >= 0 && gxb + 3 < XD) ? PINF : -PINF;
        bmask[j] = pk4(m);
    }

    auto loadq = [&](int zi, int j) -> H4 {
        if (zi < 0 || zi >= ZD || !im_ok[j]) return HINF4;
        const size_t p = (size_t)zi * PLANE + im_goff[j];
        return ldp4(inb + p);
    };

    auto s1_of = [&](const hv2* sp, int j) -> H4 {
        const hv2* p = sp + (brow[j] * SIW + bcol[j]) * 2;
        const hv2 A0 = p[1];
        const hv2 A1 = p[SIW * 2 + 1];
        const hv2 A2 = p[SIW * 4 + 1];
        const H4 B0 = *(const H4*)(p + 2);
        const H4 B1 = *(const H4*)(p + SIW * 2 + 2);
        const H4 B2 = *(const H4*)(p + SIW * 4 + 2);
        const hv2 Ah = h2min(A0, h2min(A1, A2));
        const hv2 Bl = h2min(B0.lo, h2min(B1.lo, B2.lo));
        const hv2 Bh = h2min(B0.hi, h2min(B1.hi, B2.hi));
        const hv2 S1 = shf1(Ah, Bl);
        const hv2 S2 = shf1(Bl, Bh);
        H4 r;
        r.lo = h2min(Ah, h2min(S1, Bl));
        r.hi = h2min(Bl, h2min(S2, Bh));
        return r;
    };

    H4 p2a = HINF4, p1a = HINF4;
    H4 p2b = HINF4, p1b = HINF4;
    H4 s2p1 = HNINF4, s2p2 = HNINF4;
    H4 icp1 = HZ4, icp2 = HZ4;
    float sd = 0.f, ss = 0.f;

    H4 ca0 = loadq(z0 - 2, 0);
    H4 ca1 = loadq(z0 - 2, 1);

    #pragma unroll 2
    for (int s = 0; s < TSTEPS; ++s) {
        const int zi = z0 - 2 + s;
        hv2* sp = simg[s & 1];
        *(H4*)&sp[im_addr[0]] = ca0;
        if (im_has[1]) *(H4*)&sp[im_addr[1]] = ca1;
        if (s + 1 < TSTEPS) { ca0 = loadq(zi + 1, 0); ca1 = loadq(zi + 1, 1); }
        __syncthreads();
        const int zb = zi - 1;
        const bool zbv = (s >= 2) && (zb >= 0) && (zb < ZD);
        {
            const H4 cur = s1_of(sp, 0);
            if (zbv) {
                const H4 b = h4min(h4min(p2a, p1a), cur);
                *(H4*)&sbp[2 * bqi[0]] = h4min(b, bmask[0]);
            }
            p2a = p1a; p1a = cur;
        }
        if (bhas[1]) {
            const H4 cur = s1_of(sp, 1);
            if (zbv) {
                const H4 b = h4min(h4min(p2b, p1b), cur);
                *(H4*)&sbp[2 * bqi[1]] = h4min(b, bmask[1]);
            }
            p2b = p1b; p1b = cur;
        }
        const H4 icq = *(const H4*)&sp[((ty + 2) * SIW + tx + 1) * 2];
        __syncthreads();
        H4 s2n = HNINF4;
        if (zbv) {
            const hv2* p = sbp + (ty * BWQ + tx) * 2;
            const H4 U0 = *(const H4*)p;
            const H4 U1 = *(const H4*)(p + BWQ * 2);
            const H4 U2 = *(const H4*)(p + BWQ * 4);
            const hv2 V0 = p[2];
            const hv2 V1 = p[BWQ * 2 + 2];
            const hv2 V2 = p[BWQ * 4 + 2];
            const hv2 Ul = h2max(U0.lo, h2max(U1.lo, U2.lo));
            const hv2 Uh = h2max(U0.hi, h2max(U1.hi, U2.hi));
            const hv2 Vl = h2max(V0, h2max(V1, V2));
            const hv2 S1 = shf1(Ul, Uh);
            const hv2 S2 = shf1(Uh, Vl);
            s2n.lo = h2max(Ul, h2max(S1, Uh));
            s2n.hi = h2max(Uh, h2max(S2, Vl));
        }
        if (s >= 4) {
            const int zo = zi - 2;
            const H4 d = h4max(s2p2, h4max(s2p1, s2n));
            float4 dl;
            dl.x = fmaxf((float)icp2.lo.x - (float)d.lo.x, 0.f);
            dl.y = fmaxf((float)icp2.lo.y - (float)d.lo.y, 0.f);
            dl.z = fmaxf((float)icp2.hi.x - (float)d.hi.x, 0.f);
            dl.w = fmaxf((float)icp2.hi.y - (float)d.hi.y, 0.f);
            const size_t idx = (size_t)zo * PLANE + (size_t)(y0 + ty) * XD + (x0 + 4 * tx);
            const H4 sk = ldp4(skb + idx);
            const float s0x = (float)sk.lo.x, s0y = (float)sk.lo.y;
            const float s0z = (float)sk.hi.x, s0w = (float)sk.hi.y;
            float4 sv;
            sv.x = s0x + dl.x * (1.f - s0x);
            sv.y = s0y + dl.y * (1.f - s0y);
            sv.z = s0z + dl.z * (1.f - s0z);
            sv.w = s0w + dl.w * (1.f - s0w);
            float4 w;
            if (field) {
                const float4 a = *(const float4*)(lg0 + idx);
                const float4 b = *(const float4*)(lg1 + idx);
                w = make_float4(1.f / (1.f + __expf(a.x - b.x)),
                                1.f / (1.f + __expf(a.y - b.y)),
                                1.f / (1.f + __expf(a.z - b.z)),
                                1.f / (1.f + __expf(a.w - b.w)));
            } else {
                const int4 t = *(const int4*)(tgb + idx);
                w = make_float4(t.x == 1 ? 1.f : 0.f, t.y == 1 ? 1.f : 0.f,
                                t.z == 1 ? 1.f : 0.f, t.w == 1 ? 1.f : 0.f);
            }
            sd += sv.x * w.x + sv.y * w.y + sv.z * w.z + sv.w * w.w;
            ss += sv.x + sv.y + sv.z + sv.w;
        }
        s2p2 = s2p1; s2p1 = s2n;
        icp2 = icp1; icp1 = icq;
    }

    if constexpr (MODE == 2) {
        #pragma unroll
        for (int o = 32; o; o >>= 1) {
            sd += __shfl_down(sd, o, 64);
            ss += __shfl_down(ss, o, 64);
        }
        const int w = tid >> 6;
        if ((tid & 63) == 0) { red[w][0] = sd; red[w][1] = ss; }
        __syncthreads();
        if (tid == 0) {
            float a = 0.f, b = 0.f;
            #pragma unroll
            for (int i = 0; i < 4; ++i) { a += red[i][0]; b += red[i][1]; }
            atomicAdd(&sums[2 * field + 0], a);
            atomicAdd(&sums[2 * field + 1], b);
        }
    }
}

__global__ void final_kernel(const float* __restrict__ sums, float* __restrict__ out)
{
    float tprec = (sums[0] + 1.f) / (sums[1] + 1.f);
    float tsens = (sums[2] + 1.f) / (sums[3] + 1.f);
    float cl = 2.f * tprec * tsens / (tprec + tsens + 1e-7f);
    out[0] = 1.f - cl;
}

extern "C" void kernel_launch(void* const* d_in, const int* in_sizes, int n_in,
                              void* d_out, int out_size, void* d_ws, size_t ws_size,
                              hipStream_t stream)
{
    const float* logits  = (const float*)d_in[0];
    const int*   targets = (const int*)d_in[1];
    float* out  = (float*)d_out;

    float*  sums = (float*)d_ws;
    __half* A    = (__half*)(sums + 16);
    __half* B    = A + NVOL4;
    __half* SK   = B + NVOL4;

    hipMemsetAsync(sums, 0, 16 * sizeof(float), stream);

    dim3 gf(3 * (YD / YT), ZD / FZCH, 4);  // (36, 6, 4) = 864 blocks (fused)
    dim3 gt(3 * (YD / YT), ZD / ZCH, 4);   // (36, 12, 4) = 1728 blocks (tail)
    dim3 blk(16, 16, 1);

    // pairs (0,1),(2,3),(4,5),(6,7),(8,9): 5 fused dispatches
    fused2p_kernel<0><<<gf, blk, 0, stream>>>(A, A, SK, logits, targets);  // a2 -> A
    fused2p_kernel<1><<<gf, blk, 0, stream>>>(A, B, SK, logits, targets);  // a4 -> B
    fused2p_kernel<1><<<gf, blk, 0, stream>>>(B, A, SK, logits, targets);  // a6 -> A
    fused2p_kernel<1><<<gf, blk, 0, stream>>>(A, B, SK, logits, targets);  // a8 -> B
    fused2p_kernel<1><<<gf, blk, 0, stream>>>(B, A, SK, logits, targets);  // a10 -> A
    // k = 10: read a10 (in A), in-reg skel update + weighted reduce
    fused_kernel<2><<<gt, blk, 0, stream>>>(A, B, SK, logits, targets, sums);

    final_kernel<<<1, 1, 0, stream>>>(sums, out);
}